// Round 1
// baseline (535.978 us; speedup 1.0000x reference)
//
#include <hip/hip_runtime.h>

// ProposalLayer: scores gather -> top-6000 (radix-select + bitonic sort) ->
// scrambled box decode -> NMS mask matrix -> sequential greedy scan -> [1,300,5]
//
// Constants from reference
#define N_ALL   518400   // K*H*W
#define HW      57600    // H*W
#define KANCH   9
#define WDIM    240
#define PSEL    6000
#define NPOST   300
#define ROWW    96       // mask row stride in u64 words (94 used)
#define SORTN   8192

__device__ __forceinline__ unsigned int fkey(float f) {
  // order-preserving float -> uint (larger uint == larger float)
  unsigned int u = __float_as_uint(f);
  return (u & 0x80000000u) ? ~u : (u | 0x80000000u);
}

__global__ void k_zero(unsigned int* __restrict__ p, int n) {
  int i = blockIdx.x * blockDim.x + threadIdx.x;
  if (i < n) p[i] = 0u;
}

// scores[p] = cls[0, 2k, h, w], p = k*HW + h*W + w (k-major). Store sortable key + 64K-bin hist.
__global__ void k_score_hist(const float* __restrict__ cls,
                             unsigned int* __restrict__ skey,
                             unsigned int* __restrict__ hist) {
  int p = blockIdx.x * blockDim.x + threadIdx.x;
  if (p >= N_ALL) return;
  int k = p / HW;
  int rem = p - k * HW;
  float s = cls[(2 * k) * HW + rem];
  unsigned int key = fkey(s);
  skey[p] = key;
  atomicAdd(&hist[key >> 16], 1u);
}

// find threshold bin b1 (top-16 bits) such that count(top16 >= b1) >= 6000, minimal such b1
__global__ __launch_bounds__(256) void k_find_thresh(const unsigned int* __restrict__ hist,
                                                     unsigned int* __restrict__ meta) {
  __shared__ unsigned int csum[256];
  __shared__ unsigned int chunk_sel;
  __shared__ unsigned int acc_above;
  int t = threadIdx.x;
  unsigned int s = 0;
  const unsigned int* hb = hist + t * 256;
  #pragma unroll 8
  for (int i = 0; i < 256; i++) s += hb[i];
  csum[t] = s;
  __syncthreads();
  if (t == 0) {
    unsigned int acc = 0;
    int c = 255;
    for (; c > 0; c--) {
      if (acc + csum[c] >= (unsigned)PSEL) break;
      acc += csum[c];
    }
    chunk_sel = (unsigned)c;
    acc_above = acc;
  }
  __syncthreads();
  unsigned int c = chunk_sel;
  csum[t] = hist[c * 256 + t];
  __syncthreads();
  if (t == 0) {
    unsigned int acc = acc_above;
    int b = 255;
    for (; b > 0; b--) {
      acc += csum[b];
      if (acc >= (unsigned)PSEL) break;
    }
    meta[1] = c * 256 + (unsigned)b;  // b1
  }
}

// compact all candidates with top16(key) >= b1 into composite sort keys
// stored = (~key << 32) | p  -> ascending sort == score desc, index asc (lax.top_k tie-break)
__global__ void k_compact(const unsigned int* __restrict__ skey,
                          const unsigned int* __restrict__ meta,
                          unsigned int* __restrict__ cnt,
                          unsigned long long* __restrict__ ckeys) {
  int p = blockIdx.x * blockDim.x + threadIdx.x;
  if (p >= N_ALL) return;
  unsigned int b1 = meta[1];
  unsigned int key = skey[p];
  if ((key >> 16) >= b1) {
    unsigned int pos = atomicAdd(cnt, 1u);
    if (pos < SORTN)
      ckeys[pos] = (((unsigned long long)(~key)) << 32) | (unsigned long long)(unsigned int)p;
  }
}

// single-block bitonic sort of 8192 u64 keys in LDS (64 KiB), emit first 6000 indices
__global__ __launch_bounds__(1024) void k_sort(const unsigned long long* __restrict__ ckeys,
                                               const unsigned int* __restrict__ cnt,
                                               unsigned int* __restrict__ selidx) {
  __shared__ unsigned long long lds[SORTN];
  unsigned int C = cnt[0];
  if (C > SORTN) C = SORTN;
  for (int i = threadIdx.x; i < SORTN; i += 1024)
    lds[i] = (i < (int)C) ? ckeys[i] : ~0ULL;
  for (unsigned int k = 2; k <= SORTN; k <<= 1) {
    for (unsigned int j = k >> 1; j > 0; j >>= 1) {
      __syncthreads();
      for (unsigned int t = threadIdx.x; t < SORTN / 2; t += 1024) {
        unsigned int i = 2u * t - (t & (j - 1));
        unsigned int ixj = i | j;
        unsigned long long a = lds[i], b = lds[ixj];
        bool asc = ((i & k) == 0);
        if ((a > b) == asc) { lds[i] = b; lds[ixj] = a; }
      }
    }
  }
  __syncthreads();
  for (int r = threadIdx.x; r < PSEL; r += 1024)
    selidx[r] = (unsigned int)(lds[r] & 0xFFFFFFFFull);
}

// decode score + scrambled box for each of the 6000 sorted candidates
__global__ void k_gather(const unsigned int* __restrict__ selidx,
                         const float* __restrict__ cls,
                         const float* __restrict__ bbox,
                         const float* __restrict__ anchors,
                         float4* __restrict__ boxes,
                         float* __restrict__ scores) {
  int r = blockIdx.x * blockDim.x + threadIdx.x;
  if (r >= PSEL) return;
  unsigned int p = selidx[r];
  if (p >= (unsigned)N_ALL) p = 0;  // safety (pad index should never appear)
  int kk = (int)p / HW;
  int rem = (int)p - kk * HW;
  scores[r] = cls[(2 * kk) * HW + rem];
  int k2 = (int)p % KANCH;
  int hw2 = (int)p / KANCH;
  float b[4];
  #pragma unroll
  for (int j = 0; j < 4; j++) {
    int g = (k2 * 4 + j) * HW + hw2;        // flat index into [H,W,K,4] regions buffer
    int u = g / 36;                          // original h*W+w
    int v = g - u * 36;                      // original 4*k+j (== bbox channel)
    float val = anchors[g] + bbox[v * HW + u];
    b[j] = fminf(fmaxf(val, 0.0f), 1920.0f); // clip(a+d, 0, IMAGE_SIZE), reference op order
  }
  boxes[r] = make_float4(b[0], b[1], b[2], b[3]);
}

// mask[i][bj] bit jj set iff (j>i && IoU(i,j) > 0.6), exact reference float op order
__global__ __launch_bounds__(64) void k_mask(const float4* __restrict__ boxes,
                                             unsigned long long* __restrict__ mask) {
  __shared__ float4 jb[64];
  __shared__ float  ja[64];
  int t = threadIdx.x;
  int bi = blockIdx.x, bj = blockIdx.y;
  int j0 = bj * 64;
  int j = j0 + t;
  float4 B = (j < PSEL) ? boxes[j] : make_float4(0.f, 0.f, 0.f, 0.f);
  jb[t] = B;
  ja[t] = fmaxf(B.z - B.x, 0.0f) * fmaxf(B.w - B.y, 0.0f);
  __syncthreads();
  int i = bi * 64 + t;
  if (i >= PSEL) return;
  float4 A = boxes[i];
  float aA = fmaxf(A.z - A.x, 0.0f) * fmaxf(A.w - A.y, 0.0f);
  unsigned long long word = 0ull;
  #pragma unroll 8
  for (int jj = 0; jj < 64; jj++) {
    float4 Bb = jb[jj];
    float ltx = fmaxf(A.x, Bb.x), lty = fmaxf(A.y, Bb.y);
    float rbx = fminf(A.z, Bb.z), rby = fminf(A.w, Bb.w);
    float wx = fmaxf(rbx - ltx, 0.0f), wy = fmaxf(rby - lty, 0.0f);
    float inter = wx * wy;
    float denom = fmaxf((aA + ja[jj]) - inter, 1e-9f);
    float iou = inter / denom;               // IEEE div, matches numpy
    int jg = j0 + jj;
    if (jg > i && iou > 0.6f) word |= (1ull << jj);
  }
  mask[(size_t)i * ROWW + bj] = word;
}

// single-wave sequential greedy scan; suppressed bitmap in registers (2 u64/lane);
// early break once 300 proposals kept; then write [1,300,5]
__global__ __launch_bounds__(64) void k_nms_scan(const unsigned long long* __restrict__ mask,
                                                 const float4* __restrict__ boxes,
                                                 const float* __restrict__ scores,
                                                 float* __restrict__ out) {
  int lane = threadIdx.x;
  unsigned long long s0 = 0ull, s1 = 0ull;  // lane holds words lane and 64+lane (lanes<30)
  __shared__ int list[NPOST];
  int kcount = 0;
  for (int i = 0; i < PSEL; i++) {
    int w = i >> 6, b = i & 63;
    unsigned long long cur = (w < 64) ? __shfl(s0, w) : __shfl(s1, w - 64);
    if (!((cur >> b) & 1ull)) {
      if (lane == 0) list[kcount] = i;
      kcount++;
      if (kcount == NPOST) break;
      const unsigned long long* row = mask + (size_t)i * ROWW;
      s0 |= row[lane];
      if (lane < 30) s1 |= row[64 + lane];
    }
  }
  __syncthreads();
  for (int n = lane; n < NPOST; n += 64) {
    int r = (n < kcount) ? list[n] : 0;  // nonzero(..., fill_value=0)
    float4 bx = boxes[r];
    float sc = scores[r];
    out[n * 5 + 0] = sc;
    out[n * 5 + 1] = bx.x;
    out[n * 5 + 2] = bx.y;
    out[n * 5 + 3] = bx.z;
    out[n * 5 + 4] = bx.w;
  }
}

extern "C" void kernel_launch(void* const* d_in, const int* in_sizes, int n_in,
                              void* d_out, int out_size, void* d_ws, size_t ws_size,
                              hipStream_t stream) {
  const float* cls     = (const float*)d_in[0];  // [1,18,240,240]
  const float* bbox    = (const float*)d_in[1];  // [1,36,240,240]
  const float* anchors = (const float*)d_in[2];  // [240,240,9,4]
  float* out = (float*)d_out;                    // [1,300,5] = 1500 floats

  char* ws = (char*)d_ws;
  // ws layout (~7.2 MB total)
  unsigned int*       hist   = (unsigned int*)(ws + 0);            // 65536 u32
  unsigned int*       meta   = (unsigned int*)(ws + 262144);       // [0]=cnt, [1]=b1
  unsigned int*       skey   = (unsigned int*)(ws + 262400);       // 518400 u32
  unsigned long long* ckeys  = (unsigned long long*)(ws + 2336000);// 8192 u64
  unsigned int*       selidx = (unsigned int*)(ws + 2401536);      // 6000 u32
  float4*             boxes  = (float4*)(ws + 2425536);            // 6000 float4
  float*              scores = (float*)(ws + 2521536);             // 6000 f32
  unsigned long long* mask   = (unsigned long long*)(ws + 2545536);// 6000*96 u64

  unsigned int* cnt = meta;  // meta[0]

  // 1) zero hist + meta (ws is poisoned 0xAA before every call)
  k_zero<<<(65600 + 255) / 256, 256, 0, stream>>>(hist, 65600);
  // 2) keys + histogram
  k_score_hist<<<(N_ALL + 255) / 256, 256, 0, stream>>>(cls, skey, hist);
  // 3) threshold bin
  k_find_thresh<<<1, 256, 0, stream>>>(hist, meta);
  // 4) compact candidates
  k_compact<<<(N_ALL + 255) / 256, 256, 0, stream>>>(skey, meta, cnt, ckeys);
  // 5) sort candidates, take top 6000
  k_sort<<<1, 1024, 0, stream>>>(ckeys, cnt, selidx);
  // 6) decode boxes + scores
  k_gather<<<(PSEL + 255) / 256, 256, 0, stream>>>(selidx, cls, bbox, anchors, boxes, scores);
  // 7) IoU mask matrix
  {
    dim3 g((PSEL + 63) / 64, (PSEL + 63) / 64);
    k_mask<<<g, 64, 0, stream>>>(boxes, mask);
  }
  // 8) sequential greedy NMS + output
  k_nms_scan<<<1, 64, 0, stream>>>(mask, boxes, scores, out);
}

// Round 2
// 471.518 us; speedup vs baseline: 1.1367x; 1.1367x over previous
//
#include <hip/hip_runtime.h>

// ProposalLayer: scores gather -> top-6000 (radix-select + bitonic sort) ->
// scrambled box decode -> NMS mask matrix -> tiled greedy scan -> [1,300,5]
//
// Constants from reference
#define N_ALL   518400   // K*H*W
#define HW      57600    // H*W
#define KANCH   9
#define WDIM    240
#define PSEL    6000
#define NPOST   300
#define ROWW    96       // mask row stride in u64 words (94 used)
#define SORTN   8192

__device__ __forceinline__ unsigned int fkey(float f) {
  // order-preserving float -> uint (larger uint == larger float)
  unsigned int u = __float_as_uint(f);
  return (u & 0x80000000u) ? ~u : (u | 0x80000000u);
}

__global__ void k_zero(unsigned int* __restrict__ p, int n) {
  int i = blockIdx.x * blockDim.x + threadIdx.x;
  if (i < n) p[i] = 0u;
}

// scores[p] = cls[0, 2k, h, w], p = k*HW + h*W + w (k-major). Store sortable key + 64K-bin hist.
__global__ void k_score_hist(const float* __restrict__ cls,
                             unsigned int* __restrict__ skey,
                             unsigned int* __restrict__ hist) {
  int p = blockIdx.x * blockDim.x + threadIdx.x;
  if (p >= N_ALL) return;
  int k = p / HW;
  int rem = p - k * HW;
  float s = cls[(2 * k) * HW + rem];
  unsigned int key = fkey(s);
  skey[p] = key;
  atomicAdd(&hist[key >> 16], 1u);
}

// find threshold bin b1 (top-16 bits) such that count(top16 >= b1) >= 6000, minimal such b1
__global__ __launch_bounds__(256) void k_find_thresh(const unsigned int* __restrict__ hist,
                                                     unsigned int* __restrict__ meta) {
  __shared__ unsigned int csum[256];
  __shared__ unsigned int chunk_sel;
  __shared__ unsigned int acc_above;
  int t = threadIdx.x;
  unsigned int s = 0;
  const unsigned int* hb = hist + t * 256;
  #pragma unroll 8
  for (int i = 0; i < 256; i++) s += hb[i];
  csum[t] = s;
  __syncthreads();
  if (t == 0) {
    unsigned int acc = 0;
    int c = 255;
    for (; c > 0; c--) {
      if (acc + csum[c] >= (unsigned)PSEL) break;
      acc += csum[c];
    }
    chunk_sel = (unsigned)c;
    acc_above = acc;
  }
  __syncthreads();
  unsigned int c = chunk_sel;
  csum[t] = hist[c * 256 + t];
  __syncthreads();
  if (t == 0) {
    unsigned int acc = acc_above;
    int b = 255;
    for (; b > 0; b--) {
      acc += csum[b];
      if (acc >= (unsigned)PSEL) break;
    }
    meta[1] = c * 256 + (unsigned)b;  // b1
  }
}

// compact all candidates with top16(key) >= b1 into composite sort keys
// stored = (~key << 32) | p  -> ascending sort == score desc, index asc (lax.top_k tie-break)
__global__ void k_compact(const unsigned int* __restrict__ skey,
                          const unsigned int* __restrict__ meta,
                          unsigned int* __restrict__ cnt,
                          unsigned long long* __restrict__ ckeys) {
  int p = blockIdx.x * blockDim.x + threadIdx.x;
  if (p >= N_ALL) return;
  unsigned int b1 = meta[1];
  unsigned int key = skey[p];
  if ((key >> 16) >= b1) {
    unsigned int pos = atomicAdd(cnt, 1u);
    if (pos < SORTN)
      ckeys[pos] = (((unsigned long long)(~key)) << 32) | (unsigned long long)(unsigned int)p;
  }
}

// single-block bitonic sort of 8192 u64 keys in LDS (64 KiB), emit first 6000 indices
__global__ __launch_bounds__(1024) void k_sort(const unsigned long long* __restrict__ ckeys,
                                               const unsigned int* __restrict__ cnt,
                                               unsigned int* __restrict__ selidx) {
  __shared__ unsigned long long lds[SORTN];
  unsigned int C = cnt[0];
  if (C > SORTN) C = SORTN;
  for (int i = threadIdx.x; i < SORTN; i += 1024)
    lds[i] = (i < (int)C) ? ckeys[i] : ~0ULL;
  for (unsigned int k = 2; k <= SORTN; k <<= 1) {
    for (unsigned int j = k >> 1; j > 0; j >>= 1) {
      __syncthreads();
      for (unsigned int t = threadIdx.x; t < SORTN / 2; t += 1024) {
        unsigned int i = 2u * t - (t & (j - 1));
        unsigned int ixj = i | j;
        unsigned long long a = lds[i], b = lds[ixj];
        bool asc = ((i & k) == 0);
        if ((a > b) == asc) { lds[i] = b; lds[ixj] = a; }
      }
    }
  }
  __syncthreads();
  for (int r = threadIdx.x; r < PSEL; r += 1024)
    selidx[r] = (unsigned int)(lds[r] & 0xFFFFFFFFull);
}

// decode score + scrambled box for each of the 6000 sorted candidates
__global__ void k_gather(const unsigned int* __restrict__ selidx,
                         const float* __restrict__ cls,
                         const float* __restrict__ bbox,
                         const float* __restrict__ anchors,
                         float4* __restrict__ boxes,
                         float* __restrict__ scores) {
  int r = blockIdx.x * blockDim.x + threadIdx.x;
  if (r >= PSEL) return;
  unsigned int p = selidx[r];
  if (p >= (unsigned)N_ALL) p = 0;  // safety (pad index should never appear)
  int kk = (int)p / HW;
  int rem = (int)p - kk * HW;
  scores[r] = cls[(2 * kk) * HW + rem];
  int k2 = (int)p % KANCH;
  int hw2 = (int)p / KANCH;
  float b[4];
  #pragma unroll
  for (int j = 0; j < 4; j++) {
    int g = (k2 * 4 + j) * HW + hw2;        // flat index into [H,W,K,4] regions buffer
    int u = g / 36;                          // original h*W+w
    int v = g - u * 36;                      // original 4*k+j (== bbox channel)
    float val = anchors[g] + bbox[v * HW + u];
    b[j] = fminf(fmaxf(val, 0.0f), 1920.0f); // clip(a+d, 0, IMAGE_SIZE), reference op order
  }
  boxes[r] = make_float4(b[0], b[1], b[2], b[3]);
}

// mask[i][bj] bit jj set iff (j>i && IoU(i,j) > 0.6), exact reference float op order
__global__ __launch_bounds__(64) void k_mask(const float4* __restrict__ boxes,
                                             unsigned long long* __restrict__ mask) {
  __shared__ float4 jb[64];
  __shared__ float  ja[64];
  int t = threadIdx.x;
  int bi = blockIdx.x, bj = blockIdx.y;
  int j0 = bj * 64;
  int j = j0 + t;
  float4 B = (j < PSEL) ? boxes[j] : make_float4(0.f, 0.f, 0.f, 0.f);
  jb[t] = B;
  ja[t] = fmaxf(B.z - B.x, 0.0f) * fmaxf(B.w - B.y, 0.0f);
  __syncthreads();
  int i = bi * 64 + t;
  if (i >= PSEL) return;
  float4 A = boxes[i];
  float aA = fmaxf(A.z - A.x, 0.0f) * fmaxf(A.w - A.y, 0.0f);
  unsigned long long word = 0ull;
  #pragma unroll 8
  for (int jj = 0; jj < 64; jj++) {
    float4 Bb = jb[jj];
    float ltx = fmaxf(A.x, Bb.x), lty = fmaxf(A.y, Bb.y);
    float rbx = fminf(A.z, Bb.z), rby = fminf(A.w, Bb.w);
    float wx = fmaxf(rbx - ltx, 0.0f), wy = fmaxf(rby - lty, 0.0f);
    float inter = wx * wy;
    float denom = fmaxf((aA + ja[jj]) - inter, 1e-9f);
    float iou = inter / denom;               // IEEE div, matches numpy
    int jg = j0 + jj;
    if (jg > i && iou > 0.6f) word |= (1ull << jj);
  }
  mask[(size_t)i * ROWW + bj] = word;
}

// Tiled greedy NMS scan: tiles of 128 candidates.
//  - wave 0 holds the tile's 128x2 intra-tile mask words in registers,
//    scans with ctz-skip (iterations == kept-in-tile, not tile size)
//  - all 256 threads then OR the kept rows' future columns into the LDS
//    suppression bitmap in one parallel burst (independent loads -> MLP)
//  - early break once NPOST kept
__global__ __launch_bounds__(256) void k_nms_scan(const unsigned long long* __restrict__ mask,
                                                  const float4* __restrict__ boxes,
                                                  const float* __restrict__ scores,
                                                  float* __restrict__ out) {
  __shared__ int list[NPOST];
  __shared__ unsigned long long sup[96];
  __shared__ int kc_sh;
  __shared__ int done_sh;
  int t = threadIdx.x;
  if (t < 96) sup[t] = 0ull;
  if (t == 0) { kc_sh = 0; done_sh = 0; }
  __syncthreads();

  const int NT = (PSEL + 127) / 128;  // 47 tiles
  for (int tile = 0; tile < NT; tile++) {
    int base = tile * 128;
    int kc_old = kc_sh;           // everyone reads before wave0 mutates
    __syncthreads();

    if (t < 64) {
      // load this tile's intra-tile mask words: lane l owns rows base+l, base+64+l
      int rA = base + t, rB = base + 64 + t;
      unsigned long long a0 = 0, a1 = 0, b0 = 0, b1 = 0;
      if (rA < PSEL) {
        const unsigned long long* p = mask + (size_t)rA * ROWW + 2 * tile;
        a0 = p[0]; a1 = p[1];
      }
      if (rB < PSEL) {
        const unsigned long long* p = mask + (size_t)rB * ROWW + 2 * tile;
        b0 = p[0]; b1 = p[1];
      }
      unsigned long long av0 = ~sup[2 * tile];
      unsigned long long av1 = ~sup[2 * tile + 1];
      int v = PSEL - base;  // valid candidates in this tile
      if (v < 128) {
        if (v <= 64) {
          av0 &= (v == 64) ? ~0ull : ((1ull << v) - 1ull);
          av1 = 0ull;
        } else {
          int v2 = v - 64;
          av1 &= (v2 == 64) ? ~0ull : ((1ull << v2) - 1ull);
        }
      }
      int kc = kc_old;
      while ((av0 | av1) && kc < NPOST) {
        int idx;
        if (av0) idx = __builtin_ctzll(av0);
        else     idx = 64 + __builtin_ctzll(av1);
        if (t == 0) list[kc] = base + idx;
        kc++;
        if (kc == NPOST) break;
        unsigned long long wa, wb;
        if (idx < 64) {
          wa = __shfl(a0, idx); wb = __shfl(a1, idx);
          av0 &= ~(1ull << idx);
        } else {
          wa = __shfl(b0, idx - 64); wb = __shfl(b1, idx - 64);
          av1 &= ~(1ull << (idx - 64));
        }
        av0 &= ~wa; av1 &= ~wb;
      }
      if (t == 0) {
        kc_sh = kc;
        if (kc >= NPOST) done_sh = 1;
      }
    }
    __syncthreads();
    int kc_new = kc_sh;
    if (done_sh) break;

    // batch-OR kept rows' future columns into sup (words >= 2*(tile+1))
    int m = kc_new - kc_old;
    int w0 = 2 * tile + 2;
    int nw = 94 - w0;
    if (m > 0 && nw > 0) {
      int total = m * nw;
      for (int p = t; p < total; p += 256) {
        int ri = p / nw;
        int w = w0 + (p - ri * nw);
        int r = list[kc_old + ri];
        unsigned long long vmask = mask[(size_t)r * ROWW + w];
        if (vmask) atomicOr(&sup[w], vmask);
      }
    }
    __syncthreads();  // sup complete before next tile's scan
  }
  __syncthreads();  // list visible to all

  int kc = kc_sh;
  for (int n = t; n < NPOST; n += 256) {
    int r = (n < kc) ? list[n] : 0;  // nonzero(..., fill_value=0)
    float4 bx = boxes[r];
    float sc = scores[r];
    out[n * 5 + 0] = sc;
    out[n * 5 + 1] = bx.x;
    out[n * 5 + 2] = bx.y;
    out[n * 5 + 3] = bx.z;
    out[n * 5 + 4] = bx.w;
  }
}

extern "C" void kernel_launch(void* const* d_in, const int* in_sizes, int n_in,
                              void* d_out, int out_size, void* d_ws, size_t ws_size,
                              hipStream_t stream) {
  const float* cls     = (const float*)d_in[0];  // [1,18,240,240]
  const float* bbox    = (const float*)d_in[1];  // [1,36,240,240]
  const float* anchors = (const float*)d_in[2];  // [240,240,9,4]
  float* out = (float*)d_out;                    // [1,300,5] = 1500 floats

  char* ws = (char*)d_ws;
  // ws layout (~7.2 MB total)
  unsigned int*       hist   = (unsigned int*)(ws + 0);            // 65536 u32
  unsigned int*       meta   = (unsigned int*)(ws + 262144);       // [0]=cnt, [1]=b1
  unsigned int*       skey   = (unsigned int*)(ws + 262400);       // 518400 u32
  unsigned long long* ckeys  = (unsigned long long*)(ws + 2336000);// 8192 u64
  unsigned int*       selidx = (unsigned int*)(ws + 2401536);      // 6000 u32
  float4*             boxes  = (float4*)(ws + 2425536);            // 6000 float4
  float*              scores = (float*)(ws + 2521536);             // 6000 f32
  unsigned long long* mask   = (unsigned long long*)(ws + 2545536);// 6000*96 u64

  unsigned int* cnt = meta;  // meta[0]

  // 1) zero hist + meta (ws is poisoned 0xAA before every call)
  k_zero<<<(65600 + 255) / 256, 256, 0, stream>>>(hist, 65600);
  // 2) keys + histogram
  k_score_hist<<<(N_ALL + 255) / 256, 256, 0, stream>>>(cls, skey, hist);
  // 3) threshold bin
  k_find_thresh<<<1, 256, 0, stream>>>(hist, meta);
  // 4) compact candidates
  k_compact<<<(N_ALL + 255) / 256, 256, 0, stream>>>(skey, meta, cnt, ckeys);
  // 5) sort candidates, take top 6000
  k_sort<<<1, 1024, 0, stream>>>(ckeys, cnt, selidx);
  // 6) decode boxes + scores
  k_gather<<<(PSEL + 255) / 256, 256, 0, stream>>>(selidx, cls, bbox, anchors, boxes, scores);
  // 7) IoU mask matrix
  {
    dim3 g((PSEL + 63) / 64, (PSEL + 63) / 64);
    k_mask<<<g, 64, 0, stream>>>(boxes, mask);
  }
  // 8) tiled greedy NMS + output
  k_nms_scan<<<1, 256, 0, stream>>>(mask, boxes, scores, out);
}

// Round 3
// 347.322 us; speedup vs baseline: 1.5432x; 1.3576x over previous
//
#include <hip/hip_runtime.h>

// ProposalLayer: scores gather -> top-6000 (LDS-privatized radix-select +
// bitonic sort) -> scrambled box decode -> NMS mask matrix -> tiled greedy
// scan -> [1,300,5]
//
// Constants from reference
#define N_ALL   518400   // K*H*W
#define HW      57600    // H*W
#define KANCH   9
#define WDIM    240
#define PSEL    6000
#define NPOST   300
#define ROWW    96       // mask row stride in u64 words (94 used)
#define SORTN   8192
#define BINS    8192     // top-13 bits of sortable key
#define KSHIFT  19       // 32-13
#define HBLK    64       // histogram blocks

__device__ __forceinline__ unsigned int fkey(float f) {
  // order-preserving float -> uint (larger uint == larger float)
  unsigned int u = __float_as_uint(f);
  return (u & 0x80000000u) ? ~u : (u | 0x80000000u);
}

// Per-block LDS histogram of top-13 key bits + sortable-key store.
// Zero global atomics: each block writes its partial histogram to global.
__global__ __launch_bounds__(256) void k_hist(const float* __restrict__ cls,
                                              unsigned int* __restrict__ skey,
                                              unsigned int* __restrict__ part) {
  __shared__ unsigned int h[BINS];
  int t = threadIdx.x;
  for (int i = t; i < BINS; i += 256) h[i] = 0u;
  __syncthreads();
  int gtid = blockIdx.x * 256 + t;
  const int NQ = N_ALL / 4;           // 129600 quads; HW%4==0 so no straddle
  for (int q = gtid; q < NQ; q += HBLK * 256) {
    int p = q * 4;
    int k = p / HW;
    int rem = p - k * HW;
    float4 v = *(const float4*)(cls + (2 * k) * HW + rem);
    uint4 kk;
    kk.x = fkey(v.x); kk.y = fkey(v.y); kk.z = fkey(v.z); kk.w = fkey(v.w);
    *(uint4*)(skey + p) = kk;
    atomicAdd(&h[kk.x >> KSHIFT], 1u);
    atomicAdd(&h[kk.y >> KSHIFT], 1u);
    atomicAdd(&h[kk.z >> KSHIFT], 1u);
    atomicAdd(&h[kk.w >> KSHIFT], 1u);
  }
  __syncthreads();
  unsigned int* dst = part + blockIdx.x * BINS;
  for (int i = t; i < BINS; i += 256) dst[i] = h[i];
}

// Sum the HBLK partial histograms -> hist[BINS]. Fully coalesced, no atomics.
__global__ __launch_bounds__(256) void k_reduce(const unsigned int* __restrict__ part,
                                                unsigned int* __restrict__ hist) {
  int b = blockIdx.x * 256 + threadIdx.x;
  if (b >= BINS) return;
  unsigned int s = 0;
  for (int blk = 0; blk < HBLK; blk++) s += part[blk * BINS + b];
  hist[b] = s;
}

// find threshold bin b1 (top-13 bits): minimal b1 with count(top13 >= b1) >= PSEL.
// Also zeroes the compact counter (meta[0]).
__global__ __launch_bounds__(1024) void k_find_thresh(const unsigned int* __restrict__ hist,
                                                      unsigned int* __restrict__ meta) {
  __shared__ unsigned int hh[BINS];
  __shared__ unsigned int gsum[1024];
  int t = threadIdx.x;
  uint4 a = *(const uint4*)(hist + t * 8);
  uint4 b = *(const uint4*)(hist + t * 8 + 4);
  hh[t * 8 + 0] = a.x; hh[t * 8 + 1] = a.y; hh[t * 8 + 2] = a.z; hh[t * 8 + 3] = a.w;
  hh[t * 8 + 4] = b.x; hh[t * 8 + 5] = b.y; hh[t * 8 + 6] = b.z; hh[t * 8 + 7] = b.w;
  gsum[t] = a.x + a.y + a.z + a.w + b.x + b.y + b.z + b.w;
  __syncthreads();
  if (t == 0) {
    unsigned int acc = 0;
    int g = 1023;
    for (; g > 0; g--) {
      if (acc + gsum[g] >= (unsigned)PSEL) break;
      acc += gsum[g];
    }
    int bb = g * 8 + 7;
    for (;; bb--) {
      acc += hh[bb];
      if (acc >= (unsigned)PSEL || bb == g * 8) break;
    }
    meta[1] = (unsigned)bb;  // b1
    meta[0] = 0u;            // compact counter
  }
}

// compact all candidates with top13(key) >= b1 into composite sort keys
// stored = (~key << 32) | p  -> ascending sort == score desc, index asc (lax.top_k tie-break)
__global__ __launch_bounds__(256) void k_compact(const unsigned int* __restrict__ skey,
                                                 unsigned int* __restrict__ meta,
                                                 unsigned long long* __restrict__ ckeys) {
  int q = blockIdx.x * 256 + threadIdx.x;
  const int NQ = N_ALL / 4;
  if (q >= NQ) return;
  unsigned int b1 = meta[1];
  uint4 kk = *(const uint4*)(skey + q * 4);
  unsigned int ks[4] = {kk.x, kk.y, kk.z, kk.w};
  #pragma unroll
  for (int j = 0; j < 4; j++) {
    if ((ks[j] >> KSHIFT) >= b1) {
      unsigned int pos = atomicAdd(&meta[0], 1u);
      if (pos < SORTN) {
        unsigned int p = (unsigned int)(q * 4 + j);
        ckeys[pos] = (((unsigned long long)(~ks[j])) << 32) | (unsigned long long)p;
      }
    }
  }
}

// single-block bitonic sort of 8192 u64 keys in LDS (64 KiB), emit first 6000 indices
__global__ __launch_bounds__(1024) void k_sort(const unsigned long long* __restrict__ ckeys,
                                               const unsigned int* __restrict__ meta,
                                               unsigned int* __restrict__ selidx) {
  __shared__ unsigned long long lds[SORTN];
  unsigned int C = meta[0];
  if (C > SORTN) C = SORTN;
  for (int i = threadIdx.x; i < SORTN; i += 1024)
    lds[i] = (i < (int)C) ? ckeys[i] : ~0ULL;
  for (unsigned int k = 2; k <= SORTN; k <<= 1) {
    for (unsigned int j = k >> 1; j > 0; j >>= 1) {
      __syncthreads();
      for (unsigned int t = threadIdx.x; t < SORTN / 2; t += 1024) {
        unsigned int i = 2u * t - (t & (j - 1));
        unsigned int ixj = i | j;
        unsigned long long a = lds[i], b = lds[ixj];
        bool asc = ((i & k) == 0);
        if ((a > b) == asc) { lds[i] = b; lds[ixj] = a; }
      }
    }
  }
  __syncthreads();
  for (int r = threadIdx.x; r < PSEL; r += 1024)
    selidx[r] = (unsigned int)(lds[r] & 0xFFFFFFFFull);
}

// decode score + scrambled box for each of the 6000 sorted candidates
__global__ void k_gather(const unsigned int* __restrict__ selidx,
                         const float* __restrict__ cls,
                         const float* __restrict__ bbox,
                         const float* __restrict__ anchors,
                         float4* __restrict__ boxes,
                         float* __restrict__ scores) {
  int r = blockIdx.x * blockDim.x + threadIdx.x;
  if (r >= PSEL) return;
  unsigned int p = selidx[r];
  if (p >= (unsigned)N_ALL) p = 0;  // safety (pad index should never appear)
  int kk = (int)p / HW;
  int rem = (int)p - kk * HW;
  scores[r] = cls[(2 * kk) * HW + rem];
  int k2 = (int)p % KANCH;
  int hw2 = (int)p / KANCH;
  float b[4];
  #pragma unroll
  for (int j = 0; j < 4; j++) {
    int g = (k2 * 4 + j) * HW + hw2;        // flat index into [H,W,K,4] regions buffer
    int u = g / 36;                          // original h*W+w
    int v = g - u * 36;                      // original 4*k+j (== bbox channel)
    float val = anchors[g] + bbox[v * HW + u];
    b[j] = fminf(fmaxf(val, 0.0f), 1920.0f); // clip(a+d, 0, IMAGE_SIZE), reference op order
  }
  boxes[r] = make_float4(b[0], b[1], b[2], b[3]);
}

// mask[i][bj] bit jj set iff (j>i && IoU(i,j) > 0.6), exact reference float op order
__global__ __launch_bounds__(64) void k_mask(const float4* __restrict__ boxes,
                                             unsigned long long* __restrict__ mask) {
  __shared__ float4 jb[64];
  __shared__ float  ja[64];
  int t = threadIdx.x;
  int bi = blockIdx.x, bj = blockIdx.y;
  int j0 = bj * 64;
  int j = j0 + t;
  float4 B = (j < PSEL) ? boxes[j] : make_float4(0.f, 0.f, 0.f, 0.f);
  jb[t] = B;
  ja[t] = fmaxf(B.z - B.x, 0.0f) * fmaxf(B.w - B.y, 0.0f);
  __syncthreads();
  int i = bi * 64 + t;
  if (i >= PSEL) return;
  float4 A = boxes[i];
  float aA = fmaxf(A.z - A.x, 0.0f) * fmaxf(A.w - A.y, 0.0f);
  unsigned long long word = 0ull;
  #pragma unroll 8
  for (int jj = 0; jj < 64; jj++) {
    float4 Bb = jb[jj];
    float ltx = fmaxf(A.x, Bb.x), lty = fmaxf(A.y, Bb.y);
    float rbx = fminf(A.z, Bb.z), rby = fminf(A.w, Bb.w);
    float wx = fmaxf(rbx - ltx, 0.0f), wy = fmaxf(rby - lty, 0.0f);
    float inter = wx * wy;
    float denom = fmaxf((aA + ja[jj]) - inter, 1e-9f);
    float iou = inter / denom;               // IEEE div, matches numpy
    int jg = j0 + jj;
    if (jg > i && iou > 0.6f) word |= (1ull << jj);
  }
  mask[(size_t)i * ROWW + bj] = word;
}

// Tiled greedy NMS scan: tiles of 128 candidates.
//  - wave 0 holds the tile's 128x2 intra-tile mask words in registers,
//    scans with ctz-skip (iterations == kept-in-tile, not tile size)
//  - all 256 threads then OR the kept rows' future columns into the LDS
//    suppression bitmap in one parallel burst (independent loads -> MLP)
//  - early break once NPOST kept
__global__ __launch_bounds__(256) void k_nms_scan(const unsigned long long* __restrict__ mask,
                                                  const float4* __restrict__ boxes,
                                                  const float* __restrict__ scores,
                                                  float* __restrict__ out) {
  __shared__ int list[NPOST];
  __shared__ unsigned long long sup[96];
  __shared__ int kc_sh;
  __shared__ int done_sh;
  int t = threadIdx.x;
  if (t < 96) sup[t] = 0ull;
  if (t == 0) { kc_sh = 0; done_sh = 0; }
  __syncthreads();

  const int NT = (PSEL + 127) / 128;  // 47 tiles
  for (int tile = 0; tile < NT; tile++) {
    int base = tile * 128;
    int kc_old = kc_sh;           // everyone reads before wave0 mutates
    __syncthreads();

    if (t < 64) {
      // load this tile's intra-tile mask words: lane l owns rows base+l, base+64+l
      int rA = base + t, rB = base + 64 + t;
      unsigned long long a0 = 0, a1 = 0, b0 = 0, b1 = 0;
      if (rA < PSEL) {
        const unsigned long long* p = mask + (size_t)rA * ROWW + 2 * tile;
        a0 = p[0]; a1 = p[1];
      }
      if (rB < PSEL) {
        const unsigned long long* p = mask + (size_t)rB * ROWW + 2 * tile;
        b0 = p[0]; b1 = p[1];
      }
      unsigned long long av0 = ~sup[2 * tile];
      unsigned long long av1 = ~sup[2 * tile + 1];
      int v = PSEL - base;  // valid candidates in this tile
      if (v < 128) {
        if (v <= 64) {
          av0 &= (v == 64) ? ~0ull : ((1ull << v) - 1ull);
          av1 = 0ull;
        } else {
          int v2 = v - 64;
          av1 &= (v2 == 64) ? ~0ull : ((1ull << v2) - 1ull);
        }
      }
      int kc = kc_old;
      while ((av0 | av1) && kc < NPOST) {
        int idx;
        if (av0) idx = __builtin_ctzll(av0);
        else     idx = 64 + __builtin_ctzll(av1);
        if (t == 0) list[kc] = base + idx;
        kc++;
        if (kc == NPOST) break;
        unsigned long long wa, wb;
        if (idx < 64) {
          wa = __shfl(a0, idx); wb = __shfl(a1, idx);
          av0 &= ~(1ull << idx);
        } else {
          wa = __shfl(b0, idx - 64); wb = __shfl(b1, idx - 64);
          av1 &= ~(1ull << (idx - 64));
        }
        av0 &= ~wa; av1 &= ~wb;
      }
      if (t == 0) {
        kc_sh = kc;
        if (kc >= NPOST) done_sh = 1;
      }
    }
    __syncthreads();
    int kc_new = kc_sh;
    if (done_sh) break;

    // batch-OR kept rows' future columns into sup (words >= 2*(tile+1))
    int m = kc_new - kc_old;
    int w0 = 2 * tile + 2;
    int nw = 94 - w0;
    if (m > 0 && nw > 0) {
      int total = m * nw;
      for (int p = t; p < total; p += 256) {
        int ri = p / nw;
        int w = w0 + (p - ri * nw);
        int r = list[kc_old + ri];
        unsigned long long vmask = mask[(size_t)r * ROWW + w];
        if (vmask) atomicOr(&sup[w], vmask);
      }
    }
    __syncthreads();  // sup complete before next tile's scan
  }
  __syncthreads();  // list visible to all

  int kc = kc_sh;
  for (int n = t; n < NPOST; n += 256) {
    int r = (n < kc) ? list[n] : 0;  // nonzero(..., fill_value=0)
    float4 bx = boxes[r];
    float sc = scores[r];
    out[n * 5 + 0] = sc;
    out[n * 5 + 1] = bx.x;
    out[n * 5 + 2] = bx.y;
    out[n * 5 + 3] = bx.z;
    out[n * 5 + 4] = bx.w;
  }
}

extern "C" void kernel_launch(void* const* d_in, const int* in_sizes, int n_in,
                              void* d_out, int out_size, void* d_ws, size_t ws_size,
                              hipStream_t stream) {
  const float* cls     = (const float*)d_in[0];  // [1,18,240,240]
  const float* bbox    = (const float*)d_in[1];  // [1,36,240,240]
  const float* anchors = (const float*)d_in[2];  // [240,240,9,4]
  float* out = (float*)d_out;                    // [1,300,5] = 1500 floats

  char* ws = (char*)d_ws;
  // ws layout (~12 MB total)
  unsigned int*       part   = (unsigned int*)(ws + 0);            // HBLK*BINS u32 = 2 MB
  unsigned int*       hist   = (unsigned int*)(ws + 2097152);      // 8192 u32
  unsigned int*       meta   = (unsigned int*)(ws + 2129920);      // [0]=cnt, [1]=b1
  unsigned int*       skey   = (unsigned int*)(ws + 2130176);      // 518400 u32
  unsigned long long* ckeys  = (unsigned long long*)(ws + 4203776);// 8192 u64
  unsigned int*       selidx = (unsigned int*)(ws + 4269312);      // 6000 u32
  float4*             boxes  = (float4*)(ws + 4293312);            // 6000 float4
  float*              scores = (float*)(ws + 4389312);             // 6000 f32
  unsigned long long* mask   = (unsigned long long*)(ws + 4413312);// 6000*96 u64

  // 1) keys + per-block LDS histograms (no global atomics)
  k_hist<<<HBLK, 256, 0, stream>>>(cls, skey, part);
  // 2) reduce partial histograms
  k_reduce<<<(BINS + 255) / 256, 256, 0, stream>>>(part, hist);
  // 3) threshold bin (also zeroes compact counter)
  k_find_thresh<<<1, 1024, 0, stream>>>(hist, meta);
  // 4) compact candidates
  k_compact<<<(N_ALL / 4 + 255) / 256, 256, 0, stream>>>(skey, meta, ckeys);
  // 5) sort candidates, take top 6000
  k_sort<<<1, 1024, 0, stream>>>(ckeys, meta, selidx);
  // 6) decode boxes + scores
  k_gather<<<(PSEL + 255) / 256, 256, 0, stream>>>(selidx, cls, bbox, anchors, boxes, scores);
  // 7) IoU mask matrix
  {
    dim3 g((PSEL + 63) / 64, (PSEL + 63) / 64);
    k_mask<<<g, 64, 0, stream>>>(boxes, mask);
  }
  // 8) tiled greedy NMS + output
  k_nms_scan<<<1, 256, 0, stream>>>(mask, boxes, scores, out);
}

// Round 4
// 337.037 us; speedup vs baseline: 1.5903x; 1.0305x over previous
//
#include <hip/hip_runtime.h>

// ProposalLayer: scores gather -> top-6000 (LDS-privatized radix-select +
// bitonic sort) -> scrambled box decode -> NMS mask matrix (upper-tri only)
// -> tiled greedy scan w/ diag-prefetch pipeline -> [1,300,5]
//
// Constants from reference
#define N_ALL   518400   // K*H*W
#define HW      57600    // H*W
#define KANCH   9
#define WDIM    240
#define PSEL    6000
#define NPOST   300
#define ROWW    96       // mask row stride in u64 words (94 used)
#define SORTN   8192
#define BINS    8192     // top-13 bits of sortable key
#define KSHIFT  19       // 32-13
#define HBLK    64       // histogram blocks

__device__ __forceinline__ unsigned int fkey(float f) {
  // order-preserving float -> uint (larger uint == larger float)
  unsigned int u = __float_as_uint(f);
  return (u & 0x80000000u) ? ~u : (u | 0x80000000u);
}

// Per-block LDS histogram of top-13 key bits + sortable-key store.
// Zero global atomics: each block writes its partial histogram to global.
__global__ __launch_bounds__(256) void k_hist(const float* __restrict__ cls,
                                              unsigned int* __restrict__ skey,
                                              unsigned int* __restrict__ part) {
  __shared__ unsigned int h[BINS];
  int t = threadIdx.x;
  for (int i = t; i < BINS; i += 256) h[i] = 0u;
  __syncthreads();
  int gtid = blockIdx.x * 256 + t;
  const int NQ = N_ALL / 4;           // 129600 quads; HW%4==0 so no straddle
  for (int q = gtid; q < NQ; q += HBLK * 256) {
    int p = q * 4;
    int k = p / HW;
    int rem = p - k * HW;
    float4 v = *(const float4*)(cls + (2 * k) * HW + rem);
    uint4 kk;
    kk.x = fkey(v.x); kk.y = fkey(v.y); kk.z = fkey(v.z); kk.w = fkey(v.w);
    *(uint4*)(skey + p) = kk;
    atomicAdd(&h[kk.x >> KSHIFT], 1u);
    atomicAdd(&h[kk.y >> KSHIFT], 1u);
    atomicAdd(&h[kk.z >> KSHIFT], 1u);
    atomicAdd(&h[kk.w >> KSHIFT], 1u);
  }
  __syncthreads();
  unsigned int* dst = part + blockIdx.x * BINS;
  for (int i = t; i < BINS; i += 256) dst[i] = h[i];
}

// Sum the HBLK partial histograms -> hist[BINS]. Fully coalesced, no atomics.
__global__ __launch_bounds__(256) void k_reduce(const unsigned int* __restrict__ part,
                                                unsigned int* __restrict__ hist) {
  int b = blockIdx.x * 256 + threadIdx.x;
  if (b >= BINS) return;
  unsigned int s = 0;
  for (int blk = 0; blk < HBLK; blk++) s += part[blk * BINS + b];
  hist[b] = s;
}

// find threshold bin b1 (top-13 bits): minimal b1 with count(top13 >= b1) >= PSEL.
// Also zeroes the compact counter (meta[0]).
__global__ __launch_bounds__(1024) void k_find_thresh(const unsigned int* __restrict__ hist,
                                                      unsigned int* __restrict__ meta) {
  __shared__ unsigned int hh[BINS];
  __shared__ unsigned int gsum[1024];
  int t = threadIdx.x;
  uint4 a = *(const uint4*)(hist + t * 8);
  uint4 b = *(const uint4*)(hist + t * 8 + 4);
  hh[t * 8 + 0] = a.x; hh[t * 8 + 1] = a.y; hh[t * 8 + 2] = a.z; hh[t * 8 + 3] = a.w;
  hh[t * 8 + 4] = b.x; hh[t * 8 + 5] = b.y; hh[t * 8 + 6] = b.z; hh[t * 8 + 7] = b.w;
  gsum[t] = a.x + a.y + a.z + a.w + b.x + b.y + b.z + b.w;
  __syncthreads();
  if (t == 0) {
    unsigned int acc = 0;
    int g = 1023;
    for (; g > 0; g--) {
      if (acc + gsum[g] >= (unsigned)PSEL) break;
      acc += gsum[g];
    }
    int bb = g * 8 + 7;
    for (;; bb--) {
      acc += hh[bb];
      if (acc >= (unsigned)PSEL || bb == g * 8) break;
    }
    meta[1] = (unsigned)bb;  // b1
    meta[0] = 0u;            // compact counter
  }
}

// compact all candidates with top13(key) >= b1 into composite sort keys
// stored = (~key << 32) | p  -> ascending sort == score desc, index asc (lax.top_k tie-break)
__global__ __launch_bounds__(256) void k_compact(const unsigned int* __restrict__ skey,
                                                 unsigned int* __restrict__ meta,
                                                 unsigned long long* __restrict__ ckeys) {
  int q = blockIdx.x * 256 + threadIdx.x;
  const int NQ = N_ALL / 4;
  if (q >= NQ) return;
  unsigned int b1 = meta[1];
  uint4 kk = *(const uint4*)(skey + q * 4);
  unsigned int ks[4] = {kk.x, kk.y, kk.z, kk.w};
  #pragma unroll
  for (int j = 0; j < 4; j++) {
    if ((ks[j] >> KSHIFT) >= b1) {
      unsigned int pos = atomicAdd(&meta[0], 1u);
      if (pos < SORTN) {
        unsigned int p = (unsigned int)(q * 4 + j);
        ckeys[pos] = (((unsigned long long)(~ks[j])) << 32) | (unsigned long long)p;
      }
    }
  }
}

// single-block bitonic sort of 8192 u64 keys in LDS (64 KiB), emit first 6000 indices
__global__ __launch_bounds__(1024) void k_sort(const unsigned long long* __restrict__ ckeys,
                                               const unsigned int* __restrict__ meta,
                                               unsigned int* __restrict__ selidx) {
  __shared__ unsigned long long lds[SORTN];
  unsigned int C = meta[0];
  if (C > SORTN) C = SORTN;
  for (int i = threadIdx.x; i < SORTN; i += 1024)
    lds[i] = (i < (int)C) ? ckeys[i] : ~0ULL;
  for (unsigned int k = 2; k <= SORTN; k <<= 1) {
    for (unsigned int j = k >> 1; j > 0; j >>= 1) {
      __syncthreads();
      for (unsigned int t = threadIdx.x; t < SORTN / 2; t += 1024) {
        unsigned int i = 2u * t - (t & (j - 1));
        unsigned int ixj = i | j;
        unsigned long long a = lds[i], b = lds[ixj];
        bool asc = ((i & k) == 0);
        if ((a > b) == asc) { lds[i] = b; lds[ixj] = a; }
      }
    }
  }
  __syncthreads();
  for (int r = threadIdx.x; r < PSEL; r += 1024)
    selidx[r] = (unsigned int)(lds[r] & 0xFFFFFFFFull);
}

// decode score + scrambled box for each of the 6000 sorted candidates
__global__ void k_gather(const unsigned int* __restrict__ selidx,
                         const float* __restrict__ cls,
                         const float* __restrict__ bbox,
                         const float* __restrict__ anchors,
                         float4* __restrict__ boxes,
                         float* __restrict__ scores) {
  int r = blockIdx.x * blockDim.x + threadIdx.x;
  if (r >= PSEL) return;
  unsigned int p = selidx[r];
  if (p >= (unsigned)N_ALL) p = 0;  // safety (pad index should never appear)
  int kk = (int)p / HW;
  int rem = (int)p - kk * HW;
  scores[r] = cls[(2 * kk) * HW + rem];
  int k2 = (int)p % KANCH;
  int hw2 = (int)p / KANCH;
  float b[4];
  #pragma unroll
  for (int j = 0; j < 4; j++) {
    int g = (k2 * 4 + j) * HW + hw2;        // flat index into [H,W,K,4] regions buffer
    int u = g / 36;                          // original h*W+w
    int v = g - u * 36;                      // original 4*k+j (== bbox channel)
    float val = anchors[g] + bbox[v * HW + u];
    b[j] = fminf(fmaxf(val, 0.0f), 1920.0f); // clip(a+d, 0, IMAGE_SIZE), reference op order
  }
  boxes[r] = make_float4(b[0], b[1], b[2], b[3]);
}

// mask[i][bj] bit jj set iff (j>i && IoU(i,j) > 0.6), exact reference float op order.
// Lower-triangle blocks (bj < bi&~1) are never read by the scan (phase A reads
// only diagonal words 2t..2t+1, phase B only words >= 2t+2) -> skip them.
__global__ __launch_bounds__(64) void k_mask(const float4* __restrict__ boxes,
                                             unsigned long long* __restrict__ mask) {
  int bi = blockIdx.x, bj = blockIdx.y;
  if (bj < (bi & ~1)) return;  // never-read lower triangle
  __shared__ float4 jb[64];
  __shared__ float  ja[64];
  int t = threadIdx.x;
  int j0 = bj * 64;
  int j = j0 + t;
  float4 B = (j < PSEL) ? boxes[j] : make_float4(0.f, 0.f, 0.f, 0.f);
  jb[t] = B;
  ja[t] = fmaxf(B.z - B.x, 0.0f) * fmaxf(B.w - B.y, 0.0f);
  __syncthreads();
  int i = bi * 64 + t;
  if (i >= PSEL) return;
  float4 A = boxes[i];
  float aA = fmaxf(A.z - A.x, 0.0f) * fmaxf(A.w - A.y, 0.0f);
  unsigned long long word = 0ull;
  #pragma unroll 8
  for (int jj = 0; jj < 64; jj++) {
    float4 Bb = jb[jj];
    float ltx = fmaxf(A.x, Bb.x), lty = fmaxf(A.y, Bb.y);
    float rbx = fminf(A.z, Bb.z), rby = fminf(A.w, Bb.w);
    float wx = fmaxf(rbx - ltx, 0.0f), wy = fmaxf(rby - lty, 0.0f);
    float inter = wx * wy;
    float denom = fmaxf((aA + ja[jj]) - inter, 1e-9f);
    float iou = inter / denom;               // IEEE div, matches numpy
    int jg = j0 + jj;
    if (jg > i && iou > 0.6f) word |= (1ull << jj);
  }
  mask[(size_t)i * ROWW + bj] = word;
}

// Tiled greedy NMS scan with software-pipelined diagonal prefetch:
//  - wave 0 holds tile t's 128x2 intra-tile mask words in registers; while
//    scanning tile t it issues the loads for tile t+1's words (static
//    addresses), whose s_waitcnt lands after phase B -> phase A latency
//    fully overlaps the phase-B burst.
//  - all 256 threads then OR the kept rows' future columns into the LDS
//    suppression bitmap in one parallel burst (independent loads -> MLP)
//  - early break once NPOST kept
__global__ __launch_bounds__(256) void k_nms_scan(const unsigned long long* __restrict__ mask,
                                                  const float4* __restrict__ boxes,
                                                  const float* __restrict__ scores,
                                                  float* __restrict__ out) {
  __shared__ int list[NPOST];
  __shared__ unsigned long long sup[96];
  __shared__ int kc_sh;
  __shared__ int done_sh;
  int t = threadIdx.x;
  if (t < 96) sup[t] = 0ull;
  if (t == 0) { kc_sh = 0; done_sh = 0; }

  // prefetch tile 0's diagonal words (rows 0..127 always valid)
  unsigned long long c_a0 = 0, c_a1 = 0, c_b0 = 0, c_b1 = 0;
  if (t < 64) {
    const unsigned long long* pA = mask + (size_t)t * ROWW;
    const unsigned long long* pB = mask + (size_t)(64 + t) * ROWW;
    c_a0 = pA[0]; c_a1 = pA[1];
    c_b0 = pB[0]; c_b1 = pB[1];
  }
  __syncthreads();

  const int NT = (PSEL + 127) / 128;  // 47 tiles
  for (int tile = 0; tile < NT; tile++) {
    int base = tile * 128;
    int kc_old = kc_sh;           // everyone reads before wave0 mutates
    __syncthreads();

    if (t < 64) {
      // current tile's words (loaded last iteration; waitcnt resolves here,
      // after the previous tile's phase B)
      unsigned long long a0 = c_a0, a1 = c_a1, b0 = c_b0, b1 = c_b1;
      // issue next tile's diagonal loads now; first use is next iteration
      int ntile = tile + 1;
      c_a0 = 0; c_a1 = 0; c_b0 = 0; c_b1 = 0;
      if (ntile < NT) {
        int nbase = ntile * 128;
        int rA = nbase + t, rB = nbase + 64 + t;
        if (rA < PSEL) {
          const unsigned long long* p = mask + (size_t)rA * ROWW + 2 * ntile;
          c_a0 = p[0]; c_a1 = p[1];
        }
        if (rB < PSEL) {
          const unsigned long long* p = mask + (size_t)rB * ROWW + 2 * ntile;
          c_b0 = p[0]; c_b1 = p[1];
        }
      }
      unsigned long long av0 = ~sup[2 * tile];
      unsigned long long av1 = ~sup[2 * tile + 1];
      int v = PSEL - base;  // valid candidates in this tile
      if (v < 128) {
        if (v <= 64) {
          av0 &= (v == 64) ? ~0ull : ((1ull << v) - 1ull);
          av1 = 0ull;
        } else {
          int v2 = v - 64;
          av1 &= (v2 == 64) ? ~0ull : ((1ull << v2) - 1ull);
        }
      }
      int kc = kc_old;
      while ((av0 | av1) && kc < NPOST) {
        int idx;
        if (av0) idx = __builtin_ctzll(av0);
        else     idx = 64 + __builtin_ctzll(av1);
        if (t == 0) list[kc] = base + idx;
        kc++;
        if (kc == NPOST) break;
        unsigned long long wa, wb;
        if (idx < 64) {
          wa = __shfl(a0, idx); wb = __shfl(a1, idx);
          av0 &= ~(1ull << idx);
        } else {
          wa = __shfl(b0, idx - 64); wb = __shfl(b1, idx - 64);
          av1 &= ~(1ull << (idx - 64));
        }
        av0 &= ~wa; av1 &= ~wb;
      }
      if (t == 0) {
        kc_sh = kc;
        if (kc >= NPOST) done_sh = 1;
      }
    }
    __syncthreads();
    int kc_new = kc_sh;
    if (done_sh) break;

    // batch-OR kept rows' future columns into sup (words >= 2*(tile+1))
    int m = kc_new - kc_old;
    int w0 = 2 * tile + 2;
    int nw = 94 - w0;
    if (m > 0 && nw > 0) {
      int total = m * nw;
      for (int p = t; p < total; p += 256) {
        int ri = p / nw;
        int w = w0 + (p - ri * nw);
        int r = list[kc_old + ri];
        unsigned long long vmask = mask[(size_t)r * ROWW + w];
        if (vmask) atomicOr(&sup[w], vmask);
      }
    }
    __syncthreads();  // sup complete before next tile's scan
  }
  __syncthreads();  // list visible to all

  int kc = kc_sh;
  for (int n = t; n < NPOST; n += 256) {
    int r = (n < kc) ? list[n] : 0;  // nonzero(..., fill_value=0)
    float4 bx = boxes[r];
    float sc = scores[r];
    out[n * 5 + 0] = sc;
    out[n * 5 + 1] = bx.x;
    out[n * 5 + 2] = bx.y;
    out[n * 5 + 3] = bx.z;
    out[n * 5 + 4] = bx.w;
  }
}

extern "C" void kernel_launch(void* const* d_in, const int* in_sizes, int n_in,
                              void* d_out, int out_size, void* d_ws, size_t ws_size,
                              hipStream_t stream) {
  const float* cls     = (const float*)d_in[0];  // [1,18,240,240]
  const float* bbox    = (const float*)d_in[1];  // [1,36,240,240]
  const float* anchors = (const float*)d_in[2];  // [240,240,9,4]
  float* out = (float*)d_out;                    // [1,300,5] = 1500 floats

  char* ws = (char*)d_ws;
  // ws layout (~12 MB total)
  unsigned int*       part   = (unsigned int*)(ws + 0);            // HBLK*BINS u32 = 2 MB
  unsigned int*       hist   = (unsigned int*)(ws + 2097152);      // 8192 u32
  unsigned int*       meta   = (unsigned int*)(ws + 2129920);      // [0]=cnt, [1]=b1
  unsigned int*       skey   = (unsigned int*)(ws + 2130176);      // 518400 u32
  unsigned long long* ckeys  = (unsigned long long*)(ws + 4203776);// 8192 u64
  unsigned int*       selidx = (unsigned int*)(ws + 4269312);      // 6000 u32
  float4*             boxes  = (float4*)(ws + 4293312);            // 6000 float4
  float*              scores = (float*)(ws + 4389312);             // 6000 f32
  unsigned long long* mask   = (unsigned long long*)(ws + 4413312);// 6000*96 u64

  // 1) keys + per-block LDS histograms (no global atomics)
  k_hist<<<HBLK, 256, 0, stream>>>(cls, skey, part);
  // 2) reduce partial histograms
  k_reduce<<<(BINS + 255) / 256, 256, 0, stream>>>(part, hist);
  // 3) threshold bin (also zeroes compact counter)
  k_find_thresh<<<1, 1024, 0, stream>>>(hist, meta);
  // 4) compact candidates
  k_compact<<<(N_ALL / 4 + 255) / 256, 256, 0, stream>>>(skey, meta, ckeys);
  // 5) sort candidates, take top 6000
  k_sort<<<1, 1024, 0, stream>>>(ckeys, meta, selidx);
  // 6) decode boxes + scores
  k_gather<<<(PSEL + 255) / 256, 256, 0, stream>>>(selidx, cls, bbox, anchors, boxes, scores);
  // 7) IoU mask matrix (upper triangle only)
  {
    dim3 g((PSEL + 63) / 64, (PSEL + 63) / 64);
    k_mask<<<g, 64, 0, stream>>>(boxes, mask);
  }
  // 8) tiled greedy NMS + output
  k_nms_scan<<<1, 256, 0, stream>>>(mask, boxes, scores, out);
}

// Round 5
// 306.205 us; speedup vs baseline: 1.7504x; 1.1007x over previous
//
#include <hip/hip_runtime.h>

// ProposalLayer: scores gather -> top-6000 (LDS-privatized radix-select +
// bitonic sort) -> scrambled box decode -> NMS mask matrix (upper-tri only)
// -> tiled greedy scan (iso-filtered chain + MLP-batched suppression) -> [1,300,5]
//
// Constants from reference
#define N_ALL   518400   // K*H*W
#define HW      57600    // H*W
#define KANCH   9
#define WDIM    240
#define PSEL    6000
#define NPOST   300
#define ROWW    96       // mask row stride in u64 words (94 used)
#define SORTN   8192
#define BINS    8192     // top-13 bits of sortable key
#define KSHIFT  19       // 32-13
#define HBLK    64       // histogram blocks

__device__ __forceinline__ unsigned int fkey(float f) {
  // order-preserving float -> uint (larger uint == larger float)
  unsigned int u = __float_as_uint(f);
  return (u & 0x80000000u) ? ~u : (u | 0x80000000u);
}

// Per-block LDS histogram of top-13 key bits + sortable-key store.
// Zero global atomics: each block writes its partial histogram to global.
__global__ __launch_bounds__(256) void k_hist(const float* __restrict__ cls,
                                              unsigned int* __restrict__ skey,
                                              unsigned int* __restrict__ part) {
  __shared__ unsigned int h[BINS];
  int t = threadIdx.x;
  for (int i = t; i < BINS; i += 256) h[i] = 0u;
  __syncthreads();
  int gtid = blockIdx.x * 256 + t;
  const int NQ = N_ALL / 4;           // 129600 quads; HW%4==0 so no straddle
  for (int q = gtid; q < NQ; q += HBLK * 256) {
    int p = q * 4;
    int k = p / HW;
    int rem = p - k * HW;
    float4 v = *(const float4*)(cls + (2 * k) * HW + rem);
    uint4 kk;
    kk.x = fkey(v.x); kk.y = fkey(v.y); kk.z = fkey(v.z); kk.w = fkey(v.w);
    *(uint4*)(skey + p) = kk;
    atomicAdd(&h[kk.x >> KSHIFT], 1u);
    atomicAdd(&h[kk.y >> KSHIFT], 1u);
    atomicAdd(&h[kk.z >> KSHIFT], 1u);
    atomicAdd(&h[kk.w >> KSHIFT], 1u);
  }
  __syncthreads();
  unsigned int* dst = part + blockIdx.x * BINS;
  for (int i = t; i < BINS; i += 256) dst[i] = h[i];
}

// Sum the HBLK partial histograms -> hist[BINS]. Fully coalesced, no atomics.
__global__ __launch_bounds__(256) void k_reduce(const unsigned int* __restrict__ part,
                                                unsigned int* __restrict__ hist) {
  int b = blockIdx.x * 256 + threadIdx.x;
  if (b >= BINS) return;
  unsigned int s = 0;
  for (int blk = 0; blk < HBLK; blk++) s += part[blk * BINS + b];
  hist[b] = s;
}

// find threshold bin b1 (top-13 bits): minimal b1 with count(top13 >= b1) >= PSEL.
// Also zeroes the compact counter (meta[0]).
__global__ __launch_bounds__(1024) void k_find_thresh(const unsigned int* __restrict__ hist,
                                                      unsigned int* __restrict__ meta) {
  __shared__ unsigned int hh[BINS];
  __shared__ unsigned int gsum[1024];
  int t = threadIdx.x;
  uint4 a = *(const uint4*)(hist + t * 8);
  uint4 b = *(const uint4*)(hist + t * 8 + 4);
  hh[t * 8 + 0] = a.x; hh[t * 8 + 1] = a.y; hh[t * 8 + 2] = a.z; hh[t * 8 + 3] = a.w;
  hh[t * 8 + 4] = b.x; hh[t * 8 + 5] = b.y; hh[t * 8 + 6] = b.z; hh[t * 8 + 7] = b.w;
  gsum[t] = a.x + a.y + a.z + a.w + b.x + b.y + b.z + b.w;
  __syncthreads();
  if (t == 0) {
    unsigned int acc = 0;
    int g = 1023;
    for (; g > 0; g--) {
      if (acc + gsum[g] >= (unsigned)PSEL) break;
      acc += gsum[g];
    }
    int bb = g * 8 + 7;
    for (;; bb--) {
      acc += hh[bb];
      if (acc >= (unsigned)PSEL || bb == g * 8) break;
    }
    meta[1] = (unsigned)bb;  // b1
    meta[0] = 0u;            // compact counter
  }
}

// compact all candidates with top13(key) >= b1 into composite sort keys
// stored = (~key << 32) | p  -> ascending sort == score desc, index asc (lax.top_k tie-break)
__global__ __launch_bounds__(256) void k_compact(const unsigned int* __restrict__ skey,
                                                 unsigned int* __restrict__ meta,
                                                 unsigned long long* __restrict__ ckeys) {
  int q = blockIdx.x * 256 + threadIdx.x;
  const int NQ = N_ALL / 4;
  if (q >= NQ) return;
  unsigned int b1 = meta[1];
  uint4 kk = *(const uint4*)(skey + q * 4);
  unsigned int ks[4] = {kk.x, kk.y, kk.z, kk.w};
  #pragma unroll
  for (int j = 0; j < 4; j++) {
    if ((ks[j] >> KSHIFT) >= b1) {
      unsigned int pos = atomicAdd(&meta[0], 1u);
      if (pos < SORTN) {
        unsigned int p = (unsigned int)(q * 4 + j);
        ckeys[pos] = (((unsigned long long)(~ks[j])) << 32) | (unsigned long long)p;
      }
    }
  }
}

// single-block bitonic sort of 8192 u64 keys in LDS (64 KiB), emit first 6000 indices
__global__ __launch_bounds__(1024) void k_sort(const unsigned long long* __restrict__ ckeys,
                                               const unsigned int* __restrict__ meta,
                                               unsigned int* __restrict__ selidx) {
  __shared__ unsigned long long lds[SORTN];
  unsigned int C = meta[0];
  if (C > SORTN) C = SORTN;
  for (int i = threadIdx.x; i < SORTN; i += 1024)
    lds[i] = (i < (int)C) ? ckeys[i] : ~0ULL;
  for (unsigned int k = 2; k <= SORTN; k <<= 1) {
    for (unsigned int j = k >> 1; j > 0; j >>= 1) {
      __syncthreads();
      for (unsigned int t = threadIdx.x; t < SORTN / 2; t += 1024) {
        unsigned int i = 2u * t - (t & (j - 1));
        unsigned int ixj = i | j;
        unsigned long long a = lds[i], b = lds[ixj];
        bool asc = ((i & k) == 0);
        if ((a > b) == asc) { lds[i] = b; lds[ixj] = a; }
      }
    }
  }
  __syncthreads();
  for (int r = threadIdx.x; r < PSEL; r += 1024)
    selidx[r] = (unsigned int)(lds[r] & 0xFFFFFFFFull);
}

// decode score + scrambled box for each of the 6000 sorted candidates
__global__ void k_gather(const unsigned int* __restrict__ selidx,
                         const float* __restrict__ cls,
                         const float* __restrict__ bbox,
                         const float* __restrict__ anchors,
                         float4* __restrict__ boxes,
                         float* __restrict__ scores) {
  int r = blockIdx.x * blockDim.x + threadIdx.x;
  if (r >= PSEL) return;
  unsigned int p = selidx[r];
  if (p >= (unsigned)N_ALL) p = 0;  // safety (pad index should never appear)
  int kk = (int)p / HW;
  int rem = (int)p - kk * HW;
  scores[r] = cls[(2 * kk) * HW + rem];
  int k2 = (int)p % KANCH;
  int hw2 = (int)p / KANCH;
  float b[4];
  #pragma unroll
  for (int j = 0; j < 4; j++) {
    int g = (k2 * 4 + j) * HW + hw2;        // flat index into [H,W,K,4] regions buffer
    int u = g / 36;                          // original h*W+w
    int v = g - u * 36;                      // original 4*k+j (== bbox channel)
    float val = anchors[g] + bbox[v * HW + u];
    b[j] = fminf(fmaxf(val, 0.0f), 1920.0f); // clip(a+d, 0, IMAGE_SIZE), reference op order
  }
  boxes[r] = make_float4(b[0], b[1], b[2], b[3]);
}

// mask[i][bj] bit jj set iff (j>i && IoU(i,j) > 0.6), exact reference float op order.
// Lower-triangle blocks (bj < bi&~1) are never read by the scan.
__global__ __launch_bounds__(64) void k_mask(const float4* __restrict__ boxes,
                                             unsigned long long* __restrict__ mask) {
  int bi = blockIdx.x, bj = blockIdx.y;
  if (bj < (bi & ~1)) return;  // never-read lower triangle
  __shared__ float4 jb[64];
  __shared__ float  ja[64];
  int t = threadIdx.x;
  int j0 = bj * 64;
  int j = j0 + t;
  float4 B = (j < PSEL) ? boxes[j] : make_float4(0.f, 0.f, 0.f, 0.f);
  jb[t] = B;
  ja[t] = fmaxf(B.z - B.x, 0.0f) * fmaxf(B.w - B.y, 0.0f);
  __syncthreads();
  int i = bi * 64 + t;
  if (i >= PSEL) return;
  float4 A = boxes[i];
  float aA = fmaxf(A.z - A.x, 0.0f) * fmaxf(A.w - A.y, 0.0f);
  unsigned long long word = 0ull;
  #pragma unroll 8
  for (int jj = 0; jj < 64; jj++) {
    float4 Bb = jb[jj];
    float ltx = fmaxf(A.x, Bb.x), lty = fmaxf(A.y, Bb.y);
    float rbx = fminf(A.z, Bb.z), rby = fminf(A.w, Bb.w);
    float wx = fmaxf(rbx - ltx, 0.0f), wy = fmaxf(rby - lty, 0.0f);
    float inter = wx * wy;
    float denom = fmaxf((aA + ja[jj]) - inter, 1e-9f);
    float iou = inter / denom;               // IEEE div, matches numpy
    int jg = j0 + jj;
    if (jg > i && iou > 0.6f) word |= (1ull << jj);
  }
  mask[(size_t)i * ROWW + bj] = word;
}

// Tiled greedy NMS scan (tiles of 128):
//  - isolation pre-filter: candidates whose intra-tile row is all-zero AND
//    whose column is untargeted within the tile are kept unconditionally and
//    skip the serial shfl chain (degenerate boxes, ~75%, are exactly these).
//  - the serial chain runs only over non-isolated candidates.
//  - kept order reconstructed by ctz enumeration (cheap, no shfl).
//  - phase B (suppression OR into LDS bitmap) gathers 16 mask words into
//    registers before using any -> all loads in flight together (MLP),
//    instead of a per-thread load->use serial chain.
__global__ __launch_bounds__(256) void k_nms_scan(const unsigned long long* __restrict__ mask,
                                                  const float4* __restrict__ boxes,
                                                  const float* __restrict__ scores,
                                                  float* __restrict__ out) {
  __shared__ int list[NPOST];
  __shared__ unsigned long long sup[96];
  __shared__ int kc_sh;
  __shared__ int done_sh;
  int t = threadIdx.x;
  if (t < 96) sup[t] = 0ull;
  if (t == 0) { kc_sh = 0; done_sh = 0; }

  // prefetch tile 0's diagonal words (rows 0..127 always valid)
  unsigned long long c_a0 = 0, c_a1 = 0, c_b0 = 0, c_b1 = 0;
  if (t < 64) {
    const unsigned long long* pA = mask + (size_t)t * ROWW;
    const unsigned long long* pB = mask + (size_t)(64 + t) * ROWW;
    c_a0 = pA[0]; c_a1 = pA[1];
    c_b0 = pB[0]; c_b1 = pB[1];
  }
  __syncthreads();

  const int NT = (PSEL + 127) / 128;  // 47 tiles
  for (int tile = 0; tile < NT; tile++) {
    int base = tile * 128;
    int kc_old = kc_sh;           // everyone reads before wave0 mutates
    __syncthreads();

    if (t < 64) {
      unsigned long long a0 = c_a0, a1 = c_a1, b0 = c_b0, b1 = c_b1;
      // issue next tile's diagonal loads now; first use is next iteration
      int ntile = tile + 1;
      c_a0 = 0; c_a1 = 0; c_b0 = 0; c_b1 = 0;
      if (ntile < NT) {
        int nbase = ntile * 128;
        int rA = nbase + t, rB = nbase + 64 + t;
        if (rA < PSEL) {
          const unsigned long long* p = mask + (size_t)rA * ROWW + 2 * ntile;
          c_a0 = p[0]; c_a1 = p[1];
        }
        if (rB < PSEL) {
          const unsigned long long* p = mask + (size_t)rB * ROWW + 2 * ntile;
          c_b0 = p[0]; c_b1 = p[1];
        }
      }
      unsigned long long av0 = ~sup[2 * tile];
      unsigned long long av1 = ~sup[2 * tile + 1];
      int v = PSEL - base;  // valid candidates in this tile
      if (v < 128) {
        if (v <= 64) {
          av0 &= (v == 64) ? ~0ull : ((1ull << v) - 1ull);
          av1 = 0ull;
        } else {
          int v2 = v - 64;
          av1 &= (v2 == 64) ? ~0ull : ((1ull << v2) - 1ull);
        }
      }

      // --- isolation analysis ---
      unsigned long long balA = __ballot((a0 | a1) != 0ull);  // row base+t nonzero
      unsigned long long balB = __ballot((b0 | b1) != 0ull);  // row base+64+t nonzero
      unsigned long long col0 = a0 | b0, col1 = a1 | b1;      // columns targeted
      #pragma unroll
      for (int s = 1; s < 64; s <<= 1) {
        col0 |= __shfl_xor(col0, s);
        col1 |= __shfl_xor(col1, s);
      }
      unsigned long long nonIso0 = balA | col0;
      unsigned long long nonIso1 = balB | col1;
      unsigned long long iso0 = av0 & ~nonIso0;  // kept unconditionally
      unsigned long long iso1 = av1 & ~nonIso1;

      // --- serial chain over non-isolated available candidates only ---
      unsigned long long cv0 = av0 & nonIso0, cv1 = av1 & nonIso1;
      unsigned long long ck0 = 0ull, ck1 = 0ull;  // chain-kept
      while (cv0 | cv1) {
        int idx;
        if (cv0) idx = __builtin_ctzll(cv0);
        else     idx = 64 + __builtin_ctzll(cv1);
        unsigned long long wa, wb;
        if (idx < 64) {
          ck0 |= (1ull << idx);
          cv0 &= ~(1ull << idx);
          wa = __shfl(a0, idx); wb = __shfl(a1, idx);
        } else {
          ck1 |= (1ull << (idx - 64));
          cv1 &= ~(1ull << (idx - 64));
          wa = __shfl(b0, idx - 64); wb = __shfl(b1, idx - 64);
        }
        cv0 &= ~wa; cv1 &= ~wb;
      }

      // --- in-order enumeration of kept candidates ---
      unsigned long long km0 = iso0 | ck0, km1 = iso1 | ck1;
      int kc = kc_old;
      while ((km0 | km1) && kc < NPOST) {
        int idx;
        if (km0) { idx = __builtin_ctzll(km0); km0 &= km0 - 1; }
        else     { idx = 64 + __builtin_ctzll(km1); km1 &= km1 - 1; }
        if (t == 0) list[kc] = base + idx;
        kc++;
      }
      if (t == 0) {
        kc_sh = kc;
        if (kc >= NPOST) done_sh = 1;
      }
    }
    __syncthreads();
    int kc_new = kc_sh;
    if (done_sh) break;

    // phase B: batch-OR kept rows' future columns into sup (words >= 2*(tile+1)),
    // 16-deep register gather so all global loads are in flight before use.
    int m = kc_new - kc_old;
    int w0 = 2 * tile + 2;
    int nw = 94 - w0;
    if (m > 0 && nw > 0) {
      int total = m * nw;
      for (int p0 = t; p0 < total; p0 += 256 * 16) {
        unsigned long long vals[16];
        #pragma unroll
        for (int u = 0; u < 16; u++) {
          int p = p0 + u * 256;
          vals[u] = 0ull;
          if (p < total) {
            int ri = p / nw;
            int w = w0 + (p - ri * nw);
            int r = list[kc_old + ri];
            vals[u] = mask[(size_t)r * ROWW + w];
          }
        }
        #pragma unroll
        for (int u = 0; u < 16; u++) {
          if (vals[u]) {
            int p = p0 + u * 256;
            int ri = p / nw;
            int w = w0 + (p - ri * nw);
            atomicOr(&sup[w], vals[u]);
          }
        }
      }
    }
    __syncthreads();  // sup complete before next tile's scan
  }
  __syncthreads();  // list visible to all

  int kc = kc_sh;
  for (int n = t; n < NPOST; n += 256) {
    int r = (n < kc) ? list[n] : 0;  // nonzero(..., fill_value=0)
    float4 bx = boxes[r];
    float sc = scores[r];
    out[n * 5 + 0] = sc;
    out[n * 5 + 1] = bx.x;
    out[n * 5 + 2] = bx.y;
    out[n * 5 + 3] = bx.z;
    out[n * 5 + 4] = bx.w;
  }
}

extern "C" void kernel_launch(void* const* d_in, const int* in_sizes, int n_in,
                              void* d_out, int out_size, void* d_ws, size_t ws_size,
                              hipStream_t stream) {
  const float* cls     = (const float*)d_in[0];  // [1,18,240,240]
  const float* bbox    = (const float*)d_in[1];  // [1,36,240,240]
  const float* anchors = (const float*)d_in[2];  // [240,240,9,4]
  float* out = (float*)d_out;                    // [1,300,5] = 1500 floats

  char* ws = (char*)d_ws;
  // ws layout (~12 MB total)
  unsigned int*       part   = (unsigned int*)(ws + 0);            // HBLK*BINS u32 = 2 MB
  unsigned int*       hist   = (unsigned int*)(ws + 2097152);      // 8192 u32
  unsigned int*       meta   = (unsigned int*)(ws + 2129920);      // [0]=cnt, [1]=b1
  unsigned int*       skey   = (unsigned int*)(ws + 2130176);      // 518400 u32
  unsigned long long* ckeys  = (unsigned long long*)(ws + 4203776);// 8192 u64
  unsigned int*       selidx = (unsigned int*)(ws + 4269312);      // 6000 u32
  float4*             boxes  = (float4*)(ws + 4293312);            // 6000 float4
  float*              scores = (float*)(ws + 4389312);             // 6000 f32
  unsigned long long* mask   = (unsigned long long*)(ws + 4413312);// 6000*96 u64

  // 1) keys + per-block LDS histograms (no global atomics)
  k_hist<<<HBLK, 256, 0, stream>>>(cls, skey, part);
  // 2) reduce partial histograms
  k_reduce<<<(BINS + 255) / 256, 256, 0, stream>>>(part, hist);
  // 3) threshold bin (also zeroes compact counter)
  k_find_thresh<<<1, 1024, 0, stream>>>(hist, meta);
  // 4) compact candidates
  k_compact<<<(N_ALL / 4 + 255) / 256, 256, 0, stream>>>(skey, meta, ckeys);
  // 5) sort candidates, take top 6000
  k_sort<<<1, 1024, 0, stream>>>(ckeys, meta, selidx);
  // 6) decode boxes + scores
  k_gather<<<(PSEL + 255) / 256, 256, 0, stream>>>(selidx, cls, bbox, anchors, boxes, scores);
  // 7) IoU mask matrix (upper triangle only)
  {
    dim3 g((PSEL + 63) / 64, (PSEL + 63) / 64);
    k_mask<<<g, 64, 0, stream>>>(boxes, mask);
  }
  // 8) tiled greedy NMS + output
  k_nms_scan<<<1, 256, 0, stream>>>(mask, boxes, scores, out);
}

// Round 6
// 252.292 us; speedup vs baseline: 2.1244x; 1.2137x over previous
//
#include <hip/hip_runtime.h>

// ProposalLayer: scores gather -> top-6000 (LDS-privatized radix-select +
// all-pairs rank "sort") -> scrambled box decode -> NMS mask matrix
// (upper-tri only) -> tiled greedy scan (iso-filtered chain + MLP-batched
// suppression) -> [1,300,5]
//
// Constants from reference
#define N_ALL   518400   // K*H*W
#define HW      57600    // H*W
#define KANCH   9
#define WDIM    240
#define PSEL    6000
#define NPOST   300
#define ROWW    96       // mask row stride in u64 words (94 used)
#define SORTN   8192
#define BINS    8192     // top-13 bits of sortable key
#define KSHIFT  19       // 32-13
#define HBLK    64       // histogram blocks
#define JSLICE  1024     // rank kernel j-slice (SORTN / 8)

__device__ __forceinline__ unsigned int fkey(float f) {
  // order-preserving float -> uint (larger uint == larger float)
  unsigned int u = __float_as_uint(f);
  return (u & 0x80000000u) ? ~u : (u | 0x80000000u);
}

// Per-block LDS histogram of top-13 key bits + sortable-key store.
// Zero global atomics: each block writes its partial histogram to global.
__global__ __launch_bounds__(256) void k_hist(const float* __restrict__ cls,
                                              unsigned int* __restrict__ skey,
                                              unsigned int* __restrict__ part) {
  __shared__ unsigned int h[BINS];
  int t = threadIdx.x;
  for (int i = t; i < BINS; i += 256) h[i] = 0u;
  __syncthreads();
  int gtid = blockIdx.x * 256 + t;
  const int NQ = N_ALL / 4;           // 129600 quads; HW%4==0 so no straddle
  for (int q = gtid; q < NQ; q += HBLK * 256) {
    int p = q * 4;
    int k = p / HW;
    int rem = p - k * HW;
    float4 v = *(const float4*)(cls + (2 * k) * HW + rem);
    uint4 kk;
    kk.x = fkey(v.x); kk.y = fkey(v.y); kk.z = fkey(v.z); kk.w = fkey(v.w);
    *(uint4*)(skey + p) = kk;
    atomicAdd(&h[kk.x >> KSHIFT], 1u);
    atomicAdd(&h[kk.y >> KSHIFT], 1u);
    atomicAdd(&h[kk.z >> KSHIFT], 1u);
    atomicAdd(&h[kk.w >> KSHIFT], 1u);
  }
  __syncthreads();
  unsigned int* dst = part + blockIdx.x * BINS;
  for (int i = t; i < BINS; i += 256) dst[i] = h[i];
}

// Sum the HBLK partial histograms -> hist[BINS]. Fully coalesced, no atomics.
__global__ __launch_bounds__(256) void k_reduce(const unsigned int* __restrict__ part,
                                                unsigned int* __restrict__ hist) {
  int b = blockIdx.x * 256 + threadIdx.x;
  if (b >= BINS) return;
  unsigned int s = 0;
  for (int blk = 0; blk < HBLK; blk++) s += part[blk * BINS + b];
  hist[b] = s;
}

// find threshold bin b1 (top-13 bits): minimal b1 with count(top13 >= b1) >= PSEL.
// Also zeroes the compact counter (meta[0]).
__global__ __launch_bounds__(1024) void k_find_thresh(const unsigned int* __restrict__ hist,
                                                      unsigned int* __restrict__ meta) {
  __shared__ unsigned int hh[BINS];
  __shared__ unsigned int gsum[1024];
  int t = threadIdx.x;
  uint4 a = *(const uint4*)(hist + t * 8);
  uint4 b = *(const uint4*)(hist + t * 8 + 4);
  hh[t * 8 + 0] = a.x; hh[t * 8 + 1] = a.y; hh[t * 8 + 2] = a.z; hh[t * 8 + 3] = a.w;
  hh[t * 8 + 4] = b.x; hh[t * 8 + 5] = b.y; hh[t * 8 + 6] = b.z; hh[t * 8 + 7] = b.w;
  gsum[t] = a.x + a.y + a.z + a.w + b.x + b.y + b.z + b.w;
  __syncthreads();
  if (t == 0) {
    unsigned int acc = 0;
    int g = 1023;
    for (; g > 0; g--) {
      if (acc + gsum[g] >= (unsigned)PSEL) break;
      acc += gsum[g];
    }
    int bb = g * 8 + 7;
    for (;; bb--) {
      acc += hh[bb];
      if (acc >= (unsigned)PSEL || bb == g * 8) break;
    }
    meta[1] = (unsigned)bb;  // b1
    meta[0] = 0u;            // compact counter
  }
}

// compact all candidates with top13(key) >= b1 into composite sort keys
// stored = (~key << 32) | p  -> ascending order == score desc, index asc (lax.top_k tie-break)
__global__ __launch_bounds__(256) void k_compact(const unsigned int* __restrict__ skey,
                                                 unsigned int* __restrict__ meta,
                                                 unsigned long long* __restrict__ ckeys) {
  int q = blockIdx.x * 256 + threadIdx.x;
  const int NQ = N_ALL / 4;
  if (q >= NQ) return;
  unsigned int b1 = meta[1];
  uint4 kk = *(const uint4*)(skey + q * 4);
  unsigned int ks[4] = {kk.x, kk.y, kk.z, kk.w};
  #pragma unroll
  for (int j = 0; j < 4; j++) {
    if ((ks[j] >> KSHIFT) >= b1) {
      unsigned int pos = atomicAdd(&meta[0], 1u);
      if (pos < SORTN) {
        unsigned int p = (unsigned int)(q * 4 + j);
        ckeys[pos] = (((unsigned long long)(~ks[j])) << 32) | (unsigned long long)p;
      }
    }
  }
}

// All-pairs rank: keys are DISTINCT (low 32 bits unique), so sorted position
// of key i == #{j : key[j] < key[i]}. Partial counts per 1024-key j-slice,
// 256 blocks cover the whole chip. LDS same-address broadcast reads are free.
__global__ __launch_bounds__(256) void k_rank(const unsigned long long* __restrict__ ckeys,
                                              const unsigned int* __restrict__ meta,
                                              unsigned int* __restrict__ rankp) {
  __shared__ unsigned long long jk[256];
  int C = (int)meta[0];
  if (C > SORTN) C = SORTN;
  int i = blockIdx.x * 256 + threadIdx.x;
  unsigned long long myk = (i < C) ? ckeys[i] : ~0ULL;
  int j0 = blockIdx.y * JSLICE;
  unsigned int cnt = 0;
  for (int jc = j0; jc < j0 + JSLICE; jc += 256) {
    int j = jc + threadIdx.x;
    // pad = ~0ULL: never < any real key (real low word < 518400)
    jk[threadIdx.x] = (j < C) ? ckeys[j] : ~0ULL;
    __syncthreads();
    #pragma unroll 8
    for (int u = 0; u < 256; u++) cnt += (jk[u] < myk) ? 1u : 0u;
    __syncthreads();
  }
  rankp[(size_t)blockIdx.y * SORTN + i] = cnt;
}

// Sum the 8 partial ranks; scatter top-PSEL indices into sorted order.
__global__ __launch_bounds__(256) void k_scatter(const unsigned long long* __restrict__ ckeys,
                                                 const unsigned int* __restrict__ meta,
                                                 const unsigned int* __restrict__ rankp,
                                                 unsigned int* __restrict__ selidx) {
  int i = blockIdx.x * 256 + threadIdx.x;
  int C = (int)meta[0];
  if (C > SORTN) C = SORTN;
  if (i >= C) return;
  unsigned int r = 0;
  #pragma unroll
  for (int s = 0; s < 8; s++) r += rankp[(size_t)s * SORTN + i];
  if (r < (unsigned)PSEL)
    selidx[r] = (unsigned int)(ckeys[i] & 0xFFFFFFFFull);
}

// decode score + scrambled box for each of the 6000 sorted candidates
__global__ void k_gather(const unsigned int* __restrict__ selidx,
                         const float* __restrict__ cls,
                         const float* __restrict__ bbox,
                         const float* __restrict__ anchors,
                         float4* __restrict__ boxes,
                         float* __restrict__ scores) {
  int r = blockIdx.x * blockDim.x + threadIdx.x;
  if (r >= PSEL) return;
  unsigned int p = selidx[r];
  if (p >= (unsigned)N_ALL) p = 0;  // safety (pad index should never appear)
  int kk = (int)p / HW;
  int rem = (int)p - kk * HW;
  scores[r] = cls[(2 * kk) * HW + rem];
  int k2 = (int)p % KANCH;
  int hw2 = (int)p / KANCH;
  float b[4];
  #pragma unroll
  for (int j = 0; j < 4; j++) {
    int g = (k2 * 4 + j) * HW + hw2;        // flat index into [H,W,K,4] regions buffer
    int u = g / 36;                          // original h*W+w
    int v = g - u * 36;                      // original 4*k+j (== bbox channel)
    float val = anchors[g] + bbox[v * HW + u];
    b[j] = fminf(fmaxf(val, 0.0f), 1920.0f); // clip(a+d, 0, IMAGE_SIZE), reference op order
  }
  boxes[r] = make_float4(b[0], b[1], b[2], b[3]);
}

// mask[i][bj] bit jj set iff (j>i && IoU(i,j) > 0.6), exact reference float op order.
// Lower-triangle blocks (bj < bi&~1) are never read by the scan.
__global__ __launch_bounds__(64) void k_mask(const float4* __restrict__ boxes,
                                             unsigned long long* __restrict__ mask) {
  int bi = blockIdx.x, bj = blockIdx.y;
  if (bj < (bi & ~1)) return;  // never-read lower triangle
  __shared__ float4 jb[64];
  __shared__ float  ja[64];
  int t = threadIdx.x;
  int j0 = bj * 64;
  int j = j0 + t;
  float4 B = (j < PSEL) ? boxes[j] : make_float4(0.f, 0.f, 0.f, 0.f);
  jb[t] = B;
  ja[t] = fmaxf(B.z - B.x, 0.0f) * fmaxf(B.w - B.y, 0.0f);
  __syncthreads();
  int i = bi * 64 + t;
  if (i >= PSEL) return;
  float4 A = boxes[i];
  float aA = fmaxf(A.z - A.x, 0.0f) * fmaxf(A.w - A.y, 0.0f);
  unsigned long long word = 0ull;
  #pragma unroll 8
  for (int jj = 0; jj < 64; jj++) {
    float4 Bb = jb[jj];
    float ltx = fmaxf(A.x, Bb.x), lty = fmaxf(A.y, Bb.y);
    float rbx = fminf(A.z, Bb.z), rby = fminf(A.w, Bb.w);
    float wx = fmaxf(rbx - ltx, 0.0f), wy = fmaxf(rby - lty, 0.0f);
    float inter = wx * wy;
    float denom = fmaxf((aA + ja[jj]) - inter, 1e-9f);
    float iou = inter / denom;               // IEEE div, matches numpy
    int jg = j0 + jj;
    if (jg > i && iou > 0.6f) word |= (1ull << jj);
  }
  mask[(size_t)i * ROWW + bj] = word;
}

// Tiled greedy NMS scan (tiles of 128):
//  - isolation pre-filter: candidates whose intra-tile row is all-zero AND
//    whose column is untargeted within the tile are kept unconditionally and
//    skip the serial shfl chain (degenerate boxes, ~75%, are exactly these).
//  - the serial chain runs only over non-isolated candidates.
//  - kept order reconstructed by ctz enumeration (cheap, no shfl).
//  - phase B (suppression OR into LDS bitmap) gathers 16 mask words into
//    registers before using any -> all loads in flight together (MLP).
__global__ __launch_bounds__(256) void k_nms_scan(const unsigned long long* __restrict__ mask,
                                                  const float4* __restrict__ boxes,
                                                  const float* __restrict__ scores,
                                                  float* __restrict__ out) {
  __shared__ int list[NPOST];
  __shared__ unsigned long long sup[96];
  __shared__ int kc_sh;
  __shared__ int done_sh;
  int t = threadIdx.x;
  if (t < 96) sup[t] = 0ull;
  if (t == 0) { kc_sh = 0; done_sh = 0; }

  // prefetch tile 0's diagonal words (rows 0..127 always valid)
  unsigned long long c_a0 = 0, c_a1 = 0, c_b0 = 0, c_b1 = 0;
  if (t < 64) {
    const unsigned long long* pA = mask + (size_t)t * ROWW;
    const unsigned long long* pB = mask + (size_t)(64 + t) * ROWW;
    c_a0 = pA[0]; c_a1 = pA[1];
    c_b0 = pB[0]; c_b1 = pB[1];
  }
  __syncthreads();

  const int NT = (PSEL + 127) / 128;  // 47 tiles
  for (int tile = 0; tile < NT; tile++) {
    int base = tile * 128;
    int kc_old = kc_sh;           // everyone reads before wave0 mutates
    __syncthreads();

    if (t < 64) {
      unsigned long long a0 = c_a0, a1 = c_a1, b0 = c_b0, b1 = c_b1;
      // issue next tile's diagonal loads now; first use is next iteration
      int ntile = tile + 1;
      c_a0 = 0; c_a1 = 0; c_b0 = 0; c_b1 = 0;
      if (ntile < NT) {
        int nbase = ntile * 128;
        int rA = nbase + t, rB = nbase + 64 + t;
        if (rA < PSEL) {
          const unsigned long long* p = mask + (size_t)rA * ROWW + 2 * ntile;
          c_a0 = p[0]; c_a1 = p[1];
        }
        if (rB < PSEL) {
          const unsigned long long* p = mask + (size_t)rB * ROWW + 2 * ntile;
          c_b0 = p[0]; c_b1 = p[1];
        }
      }
      unsigned long long av0 = ~sup[2 * tile];
      unsigned long long av1 = ~sup[2 * tile + 1];
      int v = PSEL - base;  // valid candidates in this tile
      if (v < 128) {
        if (v <= 64) {
          av0 &= (v == 64) ? ~0ull : ((1ull << v) - 1ull);
          av1 = 0ull;
        } else {
          int v2 = v - 64;
          av1 &= (v2 == 64) ? ~0ull : ((1ull << v2) - 1ull);
        }
      }

      // --- isolation analysis ---
      unsigned long long balA = __ballot((a0 | a1) != 0ull);  // row base+t nonzero
      unsigned long long balB = __ballot((b0 | b1) != 0ull);  // row base+64+t nonzero
      unsigned long long col0 = a0 | b0, col1 = a1 | b1;      // columns targeted
      #pragma unroll
      for (int s = 1; s < 64; s <<= 1) {
        col0 |= __shfl_xor(col0, s);
        col1 |= __shfl_xor(col1, s);
      }
      unsigned long long nonIso0 = balA | col0;
      unsigned long long nonIso1 = balB | col1;
      unsigned long long iso0 = av0 & ~nonIso0;  // kept unconditionally
      unsigned long long iso1 = av1 & ~nonIso1;

      // --- serial chain over non-isolated available candidates only ---
      unsigned long long cv0 = av0 & nonIso0, cv1 = av1 & nonIso1;
      unsigned long long ck0 = 0ull, ck1 = 0ull;  // chain-kept
      while (cv0 | cv1) {
        int idx;
        if (cv0) idx = __builtin_ctzll(cv0);
        else     idx = 64 + __builtin_ctzll(cv1);
        unsigned long long wa, wb;
        if (idx < 64) {
          ck0 |= (1ull << idx);
          cv0 &= ~(1ull << idx);
          wa = __shfl(a0, idx); wb = __shfl(a1, idx);
        } else {
          ck1 |= (1ull << (idx - 64));
          cv1 &= ~(1ull << (idx - 64));
          wa = __shfl(b0, idx - 64); wb = __shfl(b1, idx - 64);
        }
        cv0 &= ~wa; cv1 &= ~wb;
      }

      // --- in-order enumeration of kept candidates ---
      unsigned long long km0 = iso0 | ck0, km1 = iso1 | ck1;
      int kc = kc_old;
      while ((km0 | km1) && kc < NPOST) {
        int idx;
        if (km0) { idx = __builtin_ctzll(km0); km0 &= km0 - 1; }
        else     { idx = 64 + __builtin_ctzll(km1); km1 &= km1 - 1; }
        if (t == 0) list[kc] = base + idx;
        kc++;
      }
      if (t == 0) {
        kc_sh = kc;
        if (kc >= NPOST) done_sh = 1;
      }
    }
    __syncthreads();
    int kc_new = kc_sh;
    if (done_sh) break;

    // phase B: batch-OR kept rows' future columns into sup (words >= 2*(tile+1)),
    // 16-deep register gather so all global loads are in flight before use.
    int m = kc_new - kc_old;
    int w0 = 2 * tile + 2;
    int nw = 94 - w0;
    if (m > 0 && nw > 0) {
      int total = m * nw;
      for (int p0 = t; p0 < total; p0 += 256 * 16) {
        unsigned long long vals[16];
        #pragma unroll
        for (int u = 0; u < 16; u++) {
          int p = p0 + u * 256;
          vals[u] = 0ull;
          if (p < total) {
            int ri = p / nw;
            int w = w0 + (p - ri * nw);
            int r = list[kc_old + ri];
            vals[u] = mask[(size_t)r * ROWW + w];
          }
        }
        #pragma unroll
        for (int u = 0; u < 16; u++) {
          if (vals[u]) {
            int p = p0 + u * 256;
            int ri = p / nw;
            int w = w0 + (p - ri * nw);
            atomicOr(&sup[w], vals[u]);
          }
        }
      }
    }
    __syncthreads();  // sup complete before next tile's scan
  }
  __syncthreads();  // list visible to all

  int kc = kc_sh;
  for (int n = t; n < NPOST; n += 256) {
    int r = (n < kc) ? list[n] : 0;  // nonzero(..., fill_value=0)
    float4 bx = boxes[r];
    float sc = scores[r];
    out[n * 5 + 0] = sc;
    out[n * 5 + 1] = bx.x;
    out[n * 5 + 2] = bx.y;
    out[n * 5 + 3] = bx.z;
    out[n * 5 + 4] = bx.w;
  }
}

extern "C" void kernel_launch(void* const* d_in, const int* in_sizes, int n_in,
                              void* d_out, int out_size, void* d_ws, size_t ws_size,
                              hipStream_t stream) {
  const float* cls     = (const float*)d_in[0];  // [1,18,240,240]
  const float* bbox    = (const float*)d_in[1];  // [1,36,240,240]
  const float* anchors = (const float*)d_in[2];  // [240,240,9,4]
  float* out = (float*)d_out;                    // [1,300,5] = 1500 floats

  char* ws = (char*)d_ws;
  // ws layout (~8.9 MB total)
  unsigned int*       part   = (unsigned int*)(ws + 0);            // HBLK*BINS u32 = 2 MB
  unsigned int*       hist   = (unsigned int*)(ws + 2097152);      // 8192 u32
  unsigned int*       meta   = (unsigned int*)(ws + 2129920);      // [0]=cnt, [1]=b1
  unsigned int*       skey   = (unsigned int*)(ws + 2130176);      // 518400 u32
  unsigned long long* ckeys  = (unsigned long long*)(ws + 4203776);// 8192 u64
  unsigned int*       rankp  = (unsigned int*)(ws + 4269312);      // 8*8192 u32 = 256 KB
  unsigned int*       selidx = (unsigned int*)(ws + 4531456);      // 6000 u32
  float4*             boxes  = (float4*)(ws + 4555456);            // 6000 float4
  float*              scores = (float*)(ws + 4651456);             // 6000 f32
  unsigned long long* mask   = (unsigned long long*)(ws + 4675456);// 6000*96 u64

  // 1) keys + per-block LDS histograms (no global atomics)
  k_hist<<<HBLK, 256, 0, stream>>>(cls, skey, part);
  // 2) reduce partial histograms
  k_reduce<<<(BINS + 255) / 256, 256, 0, stream>>>(part, hist);
  // 3) threshold bin (also zeroes compact counter)
  k_find_thresh<<<1, 1024, 0, stream>>>(hist, meta);
  // 4) compact candidates
  k_compact<<<(N_ALL / 4 + 255) / 256, 256, 0, stream>>>(skey, meta, ckeys);
  // 5a) all-pairs partial ranks (256 blocks ~ full chip)
  {
    dim3 g(SORTN / 256, SORTN / JSLICE);  // 32 x 8
    k_rank<<<g, 256, 0, stream>>>(ckeys, meta, rankp);
  }
  // 5b) sum partials + scatter top-6000 into sorted order
  k_scatter<<<SORTN / 256, 256, 0, stream>>>(ckeys, meta, rankp, selidx);
  // 6) decode boxes + scores
  k_gather<<<(PSEL + 255) / 256, 256, 0, stream>>>(selidx, cls, bbox, anchors, boxes, scores);
  // 7) IoU mask matrix (upper triangle only)
  {
    dim3 g((PSEL + 63) / 64, (PSEL + 63) / 64);
    k_mask<<<g, 64, 0, stream>>>(boxes, mask);
  }
  // 8) tiled greedy NMS + output
  k_nms_scan<<<1, 256, 0, stream>>>(mask, boxes, scores, out);
}